// Round 1
// baseline (79246.649 us; speedup 1.0000x reference)
//
#include <hip/hip_runtime.h>
#include <hip/hip_cooperative_groups.h>
#include <math.h>

namespace cg = cooperative_groups;

#define HD     1024
#define TLEN   2048
#define G4H    4096
#define VOUTN  32000
#define NSTEP  50
#define BOS_ID 1
#define EOS_ID 2

#define NBLK 256          // cooperative grid blocks
#define NTHR 256          // threads per block (4 waves)
#define JPB  (HD / NBLK)  // 4 h-elements owned per block
#define TPB  (TLEN / NBLK)// 8 encoder timesteps per block (attention phases)
#define RPB  (VOUTN / NBLK) // 125 logit rows per block

// ---- workspace layout (float offsets); total ~43.0 MB ----
#define OFF_GX   ((size_t)0)                         // [TLEN][4H] precomputed We_ih@x + be
#define OFF_HS   (OFF_GX + (size_t)TLEN * G4H)       // [TLEN+1][HD] encoder h states (row0 = h0 = 0)
#define OFF_HD   (OFF_HS + (size_t)(TLEN + 1) * HD)  // [2][HD] decoder h double buffer
#define OFF_SC   (OFF_HD + 2 * HD)                   // [TLEN] attention scores
#define OFF_PD   (OFF_SC + TLEN)                     // [NBLK][HD] partial contexts
#define OFF_DC   (OFF_PD + (size_t)NBLK * HD)        // [HD] context d
#define OFF_HTN  (OFF_DC + HD)                       // [HD] ht_new
#define OFF_BMV  (OFF_HTN + HD)                      // [NBLK] per-block argmax value
#define OFF_INT  (OFF_BMV + NBLK)                    // ints: bmi[NBLK], state[2] = {wid, done}

// ============================================================
// Kernel 1: Gx[t][r] = be[r] + sum_k emb[src_ids[t]][k] * We_ih[r][k]
// fp32 tiled GEMM, 128x128 tile, BK=16, 256 threads, 8x8 microtile.
// ============================================================
__global__ __launch_bounds__(256) void gx_gemm(
    const int* __restrict__ src_ids,
    const float* __restrict__ emb,    // [V_IN][HD]
    const float* __restrict__ Wih,    // [4H][HD]
    const float* __restrict__ be,     // [4H]
    float* __restrict__ Gx)           // [TLEN][4H]
{
    __shared__ float As[128][17];     // X tile  (t rows, k cols)
    __shared__ float Bs[128][17];     // W tile  (r rows, k cols)
    __shared__ int   sid[128];

    const int tid = threadIdx.x;
    const int t0 = blockIdx.x * 128;  // 16 t-tiles
    const int r0 = blockIdx.y * 128;  // 32 r-tiles

    if (tid < 128) sid[tid] = src_ids[t0 + tid];
    __syncthreads();

    const int tx = tid & 15;          // r micro
    const int ty = tid >> 4;          // t micro
    const int lrow = tid >> 1;        // staging row 0..127
    const int lk   = (tid & 1) * 8;   // staging k sub-offset

    float acc[8][8];
#pragma unroll
    for (int i = 0; i < 8; ++i)
#pragma unroll
        for (int j = 0; j < 8; ++j) acc[i][j] = 0.f;

    for (int k0 = 0; k0 < HD; k0 += 16) {
        {
            const float* xa = emb + (size_t)sid[lrow] * HD + k0 + lk;
            float4 v0 = *(const float4*)xa;
            float4 v1 = *(const float4*)(xa + 4);
            As[lrow][lk + 0] = v0.x; As[lrow][lk + 1] = v0.y;
            As[lrow][lk + 2] = v0.z; As[lrow][lk + 3] = v0.w;
            As[lrow][lk + 4] = v1.x; As[lrow][lk + 5] = v1.y;
            As[lrow][lk + 6] = v1.z; As[lrow][lk + 7] = v1.w;
            const float* wb = Wih + (size_t)(r0 + lrow) * HD + k0 + lk;
            float4 w0 = *(const float4*)wb;
            float4 w1 = *(const float4*)(wb + 4);
            Bs[lrow][lk + 0] = w0.x; Bs[lrow][lk + 1] = w0.y;
            Bs[lrow][lk + 2] = w0.z; Bs[lrow][lk + 3] = w0.w;
            Bs[lrow][lk + 4] = w1.x; Bs[lrow][lk + 5] = w1.y;
            Bs[lrow][lk + 6] = w1.z; Bs[lrow][lk + 7] = w1.w;
        }
        __syncthreads();
#pragma unroll
        for (int kk = 0; kk < 16; ++kk) {
            float a[8], bv[8];
#pragma unroll
            for (int i = 0; i < 8; ++i) a[i]  = As[ty * 8 + i][kk];
#pragma unroll
            for (int j = 0; j < 8; ++j) bv[j] = Bs[tx * 8 + j][kk];
#pragma unroll
            for (int i = 0; i < 8; ++i)
#pragma unroll
                for (int j = 0; j < 8; ++j)
                    acc[i][j] = fmaf(a[i], bv[j], acc[i][j]);
        }
        __syncthreads();
    }

    float bev[8];
#pragma unroll
    for (int j = 0; j < 8; ++j) bev[j] = be[r0 + tx * 8 + j];
#pragma unroll
    for (int i = 0; i < 8; ++i) {
        const int t = t0 + ty * 8 + i;
        float* dst = Gx + (size_t)t * G4H + r0 + tx * 8;
#pragma unroll
        for (int j = 0; j < 8; ++j) dst[j] = acc[i][j] + bev[j];
    }
}

// ============================================================
// Kernel 2: cooperative — encoder recurrence + greedy attention decoder.
// 256 blocks x 256 threads. Block b owns h-elements j0..j0+3 (j0 = 4b) and
// the 16 gate rows {g*HD + j0 + jl}. We_hh rows live in VGPRs (64/thread).
// ============================================================
__global__ __launch_bounds__(256) void seq_kernel(
    const float* __restrict__ Whh,    // We_hh [4H][HD]
    const float* __restrict__ embT,   // embed_target [VOUT][HD]
    const float* __restrict__ Wdih,   // [4H][HD]
    const float* __restrict__ Wdhh,   // [4H][HD]
    const float* __restrict__ bdv,    // [4H]
    const float* __restrict__ Wattn,  // [HD][2HD]
    const float* __restrict__ battn,  // [HD]
    const float* __restrict__ Wout,   // [VOUT][HD]
    const float* __restrict__ bout,   // [VOUT]
    float* __restrict__ wsf,
    float* __restrict__ out)          // [50 + 50*VOUT] fp32
{
    cg::grid_group grid = cg::this_grid();
    const int b    = blockIdx.x;
    const int tid  = threadIdx.x;
    const int w    = tid >> 6;   // wave 0..3
    const int lane = tid & 63;
    const int j0   = b * JPB;

    float* Gx   = wsf + OFF_GX;
    float* hs   = wsf + OFF_HS;
    float* hd   = wsf + OFF_HD;
    float* sc   = wsf + OFF_SC;
    float* pd   = wsf + OFF_PD;
    float* dctx = wsf + OFF_DC;
    float* htn  = wsf + OFF_HTN;
    float* bmv  = wsf + OFF_BMV;
    int*   bmi  = (int*)(wsf + OFF_INT);
    int*   state = bmi + NBLK;   // [0]=wid [1]=done

    __shared__ float bufAB[2 * HD];  // staging (h / x+h / d+ht / htn)
    __shared__ float g_s[4 * JPB];
    __shared__ float c_s[JPB];
    __shared__ float red[NTHR];
    __shared__ int   redi[NTHR];
    __shared__ float wt_s[TPB];

    // ---- load We_hh slice into registers: wave w = gate w, rows j0..j0+3 ----
    float wreg[4][16];
#pragma unroll
    for (int d = 0; d < 4; ++d) {
        const int grow = w * HD + j0 + d;      // gate w, element j0+d
        const float* src = Whh + (size_t)grow * HD + lane;
#pragma unroll
        for (int q = 0; q < 16; ++q) wreg[d][q] = src[q * 64];
    }

    // ---- init ----
    if (tid < JPB) { hs[j0 + tid] = 0.f; c_s[tid] = 0.f; }
    if (b == 0 && tid == 0) { state[0] = BOS_ID; state[1] = 0; }
    grid.sync();

    // ================= encoder: 2048 sequential steps =================
    for (int t = 0; t < TLEN; ++t) {
        const float* hprev = hs + (size_t)t * HD;
        for (int i = tid; i < HD; i += NTHR) bufAB[i] = hprev[i];
        __syncthreads();

        float acc[4];
#pragma unroll
        for (int d = 0; d < 4; ++d) {
            float a = 0.f;
#pragma unroll
            for (int q = 0; q < 16; ++q)
                a = fmaf(wreg[d][q], bufAB[q * 64 + lane], a);
#pragma unroll
            for (int off = 32; off > 0; off >>= 1) a += __shfl_down(a, off);
            acc[d] = a;
        }
        if (lane == 0) {
#pragma unroll
            for (int d = 0; d < 4; ++d) g_s[w * 4 + d] = acc[d];
        }
        __syncthreads();

        if (tid < JPB) {
            const int j = j0 + tid;
            const float* gx = Gx + (size_t)t * G4H;
            const float gi = g_s[0 * 4 + tid] + gx[0 * HD + j];
            const float gf = g_s[1 * 4 + tid] + gx[1 * HD + j];
            const float gg = g_s[2 * 4 + tid] + gx[2 * HD + j];
            const float go = g_s[3 * 4 + tid] + gx[3 * HD + j];
            const float i_ = 1.f / (1.f + expf(-gi));
            const float f_ = 1.f / (1.f + expf(-gf));
            const float o_ = 1.f / (1.f + expf(-go));
            const float g2 = tanhf(gg);
            const float c2 = f_ * c_s[tid] + i_ * g2;
            c_s[tid] = c2;
            hs[(size_t)(t + 1) * HD + j] = o_ * tanhf(c2);
        }
        grid.sync();
    }

    // decoder h init: hd[0] = hT ; c continues in c_s (= cT)
    if (tid < JPB) hd[j0 + tid] = hs[(size_t)TLEN * HD + j0 + tid];
    grid.sync();

    // ================= decoder: 50 greedy steps =================
    for (int s = 0; s < NSTEP; ++s) {
        float* hcur = hd + (s & 1) * HD;
        float* hnxt = hd + ((s + 1) & 1) * HD;

        // ---- ph1: LSTM gates g = Wd_ih@x + Wd_hh@h + bd ----
        {
            const int widv = state[0];
            const float* x = embT + (size_t)widv * HD;
            for (int i = tid; i < HD; i += NTHR) {
                bufAB[i] = x[i];
                bufAB[HD + i] = hcur[i];
            }
            __syncthreads();
#pragma unroll
            for (int d = 0; d < 4; ++d) {
                const int grow = w * HD + j0 + d;
                const float* wi = Wdih + (size_t)grow * HD;
                const float* wh = Wdhh + (size_t)grow * HD;
                float a = 0.f;
                for (int k = lane; k < HD; k += 64)
                    a = fmaf(wi[k], bufAB[k], fmaf(wh[k], bufAB[HD + k], a));
#pragma unroll
                for (int off = 32; off > 0; off >>= 1) a += __shfl_down(a, off);
                if (lane == 0) g_s[w * 4 + d] = a;
            }
            __syncthreads();
            if (tid < JPB) {
                const int j = j0 + tid;
                const float gi = g_s[0 * 4 + tid] + bdv[0 * HD + j];
                const float gf = g_s[1 * 4 + tid] + bdv[1 * HD + j];
                const float gg = g_s[2 * 4 + tid] + bdv[2 * HD + j];
                const float go = g_s[3 * 4 + tid] + bdv[3 * HD + j];
                const float i_ = 1.f / (1.f + expf(-gi));
                const float f_ = 1.f / (1.f + expf(-gf));
                const float o_ = 1.f / (1.f + expf(-go));
                const float g2 = tanhf(gg);
                const float c2 = f_ * c_s[tid] + i_ * g2;
                c_s[tid] = c2;
                hnxt[j] = o_ * tanhf(c2);
            }
        }
        grid.sync();

        // ---- ph2: scores sc[t] = hs[t+1] . ht  (8 t per block) ----
        for (int i = tid; i < HD; i += NTHR) bufAB[i] = hnxt[i];
        __syncthreads();
#pragma unroll
        for (int d = 0; d < 2; ++d) {
            const int t = b * TPB + w * 2 + d;
            const float* hrow = hs + (size_t)(t + 1) * HD;
            float a = 0.f;
            for (int k = lane; k < HD; k += 64) a = fmaf(hrow[k], bufAB[k], a);
#pragma unroll
            for (int off = 32; off > 0; off >>= 1) a += __shfl_down(a, off);
            if (lane == 0) sc[t] = a;
        }
        grid.sync();

        // ---- ph3: softmax stats (redundant per block) + partial context ----
        {
            float lm = -INFINITY;
            for (int t = tid; t < TLEN; t += NTHR) lm = fmaxf(lm, sc[t]);
            red[tid] = lm; __syncthreads();
            for (int s2 = NTHR / 2; s2 > 0; s2 >>= 1) {
                if (tid < s2) red[tid] = fmaxf(red[tid], red[tid + s2]);
                __syncthreads();
            }
            const float m = red[0]; __syncthreads();
            float lz = 0.f;
            for (int t = tid; t < TLEN; t += NTHR) lz += expf(sc[t] - m);
            red[tid] = lz; __syncthreads();
            for (int s2 = NTHR / 2; s2 > 0; s2 >>= 1) {
                if (tid < s2) red[tid] += red[tid + s2];
                __syncthreads();
            }
            const float Zi = 1.f / red[0]; __syncthreads();
            if (tid < TPB) wt_s[tid] = expf(sc[b * TPB + tid] - m) * Zi;
            __syncthreads();
#pragma unroll
            for (int jj = 0; jj < HD / NTHR; ++jj) {
                const int j = tid + jj * NTHR;
                float a = 0.f;
#pragma unroll
                for (int d = 0; d < TPB; ++d)
                    a = fmaf(wt_s[d], hs[(size_t)(b * TPB + d + 1) * HD + j], a);
                pd[(size_t)b * HD + j] = a;
            }
        }
        grid.sync();

        // ---- ph4: reduce partial contexts -> dctx (one wave per owned j) ----
        {
            const int j = j0 + w;   // w in 0..3 == JPB
            float a = 0.f;
#pragma unroll
            for (int q = 0; q < NBLK / 64; ++q)
                a += pd[(size_t)(lane + q * 64) * HD + j];
#pragma unroll
            for (int off = 32; off > 0; off >>= 1) a += __shfl_down(a, off);
            if (lane == 0) dctx[j] = a;
        }
        grid.sync();

        // ---- ph5: ht_new = tanh(W_attn @ [d; ht] + b_attn) ----
        for (int i = tid; i < HD; i += NTHR) {
            bufAB[i] = dctx[i];
            bufAB[HD + i] = hnxt[i];
        }
        __syncthreads();
        {
            const int j = j0 + w;
            const float* wr = Wattn + (size_t)j * (2 * HD);
            float a = 0.f;
            for (int k = lane; k < 2 * HD; k += 64) a = fmaf(wr[k], bufAB[k], a);
#pragma unroll
            for (int off = 32; off > 0; off >>= 1) a += __shfl_down(a, off);
            if (lane == 0) htn[j] = tanhf(a + battn[j]);
        }
        grid.sync();

        // ---- ph6: logits = W_out @ ht_new + b_out ; masked write ; block argmax ----
        for (int i = tid; i < HD; i += NTHR) bufAB[i] = htn[i];
        __syncthreads();
        {
            const int donev = state[1];
            const int r0 = b * RPB;
            float bv = -INFINITY; int bi = 0x7fffffff;
            for (int r = r0 + w; r < r0 + RPB; r += 4) {
                const float* wr = Wout + (size_t)r * HD;
                float a = 0.f;
                for (int k = lane; k < HD; k += 64) a = fmaf(wr[k], bufAB[k], a);
#pragma unroll
                for (int off = 32; off > 0; off >>= 1) a += __shfl_down(a, off);
                if (lane == 0) {
                    a += bout[r];
                    out[NSTEP + (size_t)s * VOUTN + r] = donev ? 0.f : a;
                    if (a > bv || (a == bv && r < bi)) { bv = a; bi = r; }
                }
            }
            if (lane == 0) { red[w] = bv; redi[w] = bi; }
            __syncthreads();
            if (tid == 0) {
                float v = red[0]; int ii = redi[0];
#pragma unroll
                for (int q = 1; q < 4; ++q)
                    if (red[q] > v || (red[q] == v && redi[q] < ii)) { v = red[q]; ii = redi[q]; }
                bmv[b] = v; bmi[b] = ii;
            }
        }
        grid.sync();

        // ---- ph7: global argmax (first index on ties) + state/token ----
        if (b == 0) {
            red[tid] = bmv[tid]; redi[tid] = bmi[tid];
            __syncthreads();
            for (int s2 = NTHR / 2; s2 > 0; s2 >>= 1) {
                if (tid < s2) {
                    if (red[tid + s2] > red[tid] ||
                        (red[tid + s2] == red[tid] && redi[tid + s2] < redi[tid])) {
                        red[tid] = red[tid + s2]; redi[tid] = redi[tid + s2];
                    }
                }
                __syncthreads();
            }
            if (tid == 0) {
                const int nid = redi[0];
                const int olddone = state[1];
                out[s] = olddone ? 0.f : (float)nid;
                state[0] = nid;
                state[1] = olddone | (nid == EOS_ID);
            }
        }
        grid.sync();
    }
}

extern "C" void kernel_launch(void* const* d_in, const int* in_sizes, int n_in,
                              void* d_out, int out_size, void* d_ws, size_t ws_size,
                              hipStream_t stream) {
    (void)in_sizes; (void)n_in; (void)out_size; (void)ws_size;
    const int*   src_ids = (const int*)  d_in[0];
    const float* emb_in  = (const float*)d_in[1];
    const float* We_ih   = (const float*)d_in[2];
    const float* We_hh   = (const float*)d_in[3];
    const float* be      = (const float*)d_in[4];
    const float* emb_tgt = (const float*)d_in[5];
    const float* Wd_ih   = (const float*)d_in[6];
    const float* Wd_hh   = (const float*)d_in[7];
    const float* bd      = (const float*)d_in[8];
    const float* W_attn  = (const float*)d_in[9];
    const float* b_attn  = (const float*)d_in[10];
    const float* W_out   = (const float*)d_in[11];
    const float* b_out   = (const float*)d_in[12];

    float* outp = (float*)d_out;
    float* wsf  = (float*)d_ws;   // needs ~43 MB

    // Phase 1: Gx = X @ We_ih^T + be   (parallel GEMM)
    dim3 g1(TLEN / 128, G4H / 128);
    gx_gemm<<<g1, 256, 0, stream>>>(src_ids, emb_in, We_ih, be, wsf + OFF_GX);

    // Phase 2: cooperative sequential kernel (encoder + decoder)
    const float* a_Whh  = We_hh;  const float* a_embT = emb_tgt;
    const float* a_Wdih = Wd_ih;  const float* a_Wdhh = Wd_hh;
    const float* a_bd   = bd;     const float* a_Wat  = W_attn;
    const float* a_bat  = b_attn; const float* a_Wout = W_out;
    const float* a_bout = b_out;
    float* a_ws = wsf; float* a_out = outp;
    void* args[] = { &a_Whh, &a_embT, &a_Wdih, &a_Wdhh, &a_bd,
                     &a_Wat, &a_bat, &a_Wout, &a_bout, &a_ws, &a_out };
    hipLaunchCooperativeKernel(reinterpret_cast<void*>(seq_kernel),
                               dim3(NBLK), dim3(NTHR), args, 0, stream);
}

// Round 2
// 27701.233 us; speedup vs baseline: 2.8608x; 2.8608x over previous
//
#include <hip/hip_runtime.h>
#include <hip/hip_cooperative_groups.h>
#include <math.h>

namespace cg = cooperative_groups;

#define HD     1024
#define TLEN   2048
#define G4H    4096
#define VOUTN  32000
#define NSTEP  50
#define BOS_ID 1
#define EOS_ID 2

// ---- decoder grid ----
#define NBLK 256
#define NTHR 256
#define JPB  (HD / NBLK)     // 4
#define TPB  (TLEN / NBLK)   // 8
#define RPB  (VOUTN / NBLK)  // 125

// ---- encoder grid ----
#define ENBLK 64
#define ENTHR 1024
#define EJPB  (HD / ENBLK)   // 16 h-elements per block

// ---- workspace layout (float offsets) ----
#define OFF_GX   ((size_t)0)                          // [TLEN][4H]
#define OFF_HS   (OFF_GX + (size_t)TLEN * G4H)        // [TLEN+1][HD]
#define OFF_HD   (OFF_HS + (size_t)(TLEN + 1) * HD)   // [2][HD]
#define OFF_SC   (OFF_HD + 2 * HD)                    // [TLEN]
#define OFF_PD   (OFF_SC + TLEN)                      // [NBLK][HD]
#define OFF_DC   (OFF_PD + (size_t)NBLK * HD)         // [HD]
#define OFF_HTN  (OFF_DC + HD)                        // [HD]
#define OFF_BMV  (OFF_HTN + HD)                       // [NBLK]
#define OFF_INT  (OFF_BMV + NBLK)                     // bmi[NBLK] + state[2] (ints)
#define OFF_CT   (OFF_INT + NBLK + 16)                // [HD] encoder cell state out
#define OFF_ARR  (OFF_CT + HD)                        // [ENBLK*16] int flags (64B apart)

#define DEV_SCOPE __HIP_MEMORY_SCOPE_AGENT

// ============================================================
// Kernel 1: Gx[t][r] = be[r] + sum_k emb[src_ids[t]][k] * We_ih[r][k]
// ============================================================
__global__ __launch_bounds__(256) void gx_gemm(
    const int* __restrict__ src_ids,
    const float* __restrict__ emb,
    const float* __restrict__ Wih,
    const float* __restrict__ be,
    float* __restrict__ Gx)
{
    __shared__ float As[128][17];
    __shared__ float Bs[128][17];
    __shared__ int   sid[128];

    const int tid = threadIdx.x;
    const int t0 = blockIdx.x * 128;
    const int r0 = blockIdx.y * 128;

    if (tid < 128) sid[tid] = src_ids[t0 + tid];
    __syncthreads();

    const int tx = tid & 15;
    const int ty = tid >> 4;
    const int lrow = tid >> 1;
    const int lk   = (tid & 1) * 8;

    float acc[8][8];
#pragma unroll
    for (int i = 0; i < 8; ++i)
#pragma unroll
        for (int j = 0; j < 8; ++j) acc[i][j] = 0.f;

    for (int k0 = 0; k0 < HD; k0 += 16) {
        {
            const float* xa = emb + (size_t)sid[lrow] * HD + k0 + lk;
            float4 v0 = *(const float4*)xa;
            float4 v1 = *(const float4*)(xa + 4);
            As[lrow][lk + 0] = v0.x; As[lrow][lk + 1] = v0.y;
            As[lrow][lk + 2] = v0.z; As[lrow][lk + 3] = v0.w;
            As[lrow][lk + 4] = v1.x; As[lrow][lk + 5] = v1.y;
            As[lrow][lk + 6] = v1.z; As[lrow][lk + 7] = v1.w;
            const float* wb = Wih + (size_t)(r0 + lrow) * HD + k0 + lk;
            float4 w0 = *(const float4*)wb;
            float4 w1 = *(const float4*)(wb + 4);
            Bs[lrow][lk + 0] = w0.x; Bs[lrow][lk + 1] = w0.y;
            Bs[lrow][lk + 2] = w0.z; Bs[lrow][lk + 3] = w0.w;
            Bs[lrow][lk + 4] = w1.x; Bs[lrow][lk + 5] = w1.y;
            Bs[lrow][lk + 6] = w1.z; Bs[lrow][lk + 7] = w1.w;
        }
        __syncthreads();
#pragma unroll
        for (int kk = 0; kk < 16; ++kk) {
            float a[8], bv[8];
#pragma unroll
            for (int i = 0; i < 8; ++i) a[i]  = As[ty * 8 + i][kk];
#pragma unroll
            for (int j = 0; j < 8; ++j) bv[j] = Bs[tx * 8 + j][kk];
#pragma unroll
            for (int i = 0; i < 8; ++i)
#pragma unroll
                for (int j = 0; j < 8; ++j)
                    acc[i][j] = fmaf(a[i], bv[j], acc[i][j]);
        }
        __syncthreads();
    }

    float bev[8];
#pragma unroll
    for (int j = 0; j < 8; ++j) bev[j] = be[r0 + tx * 8 + j];
#pragma unroll
    for (int i = 0; i < 8; ++i) {
        const int t = t0 + ty * 8 + i;
        float* dst = Gx + (size_t)t * G4H + r0 + tx * 8;
#pragma unroll
        for (int j = 0; j < 8; ++j) dst[j] = acc[i][j] + bev[j];
    }
}

// ============================================================
// Kernel 2: encoder recurrence. 64 blocks x 1024 threads.
// Block b owns h-elements j0..j0+15 (64 gate rows, register-resident).
// Cross-block exchange via device-scope atomics + flag array (no grid.sync).
// ============================================================
__global__ __launch_bounds__(1024, 4) void enc_kernel(
    const float* __restrict__ Whh,    // [4H][HD]
    const float* __restrict__ Gx,     // [TLEN][4H] (be folded in)
    float* __restrict__ hs,           // [TLEN+1][HD]; row 0 pre-zeroed
    float* __restrict__ ct,           // [HD] cell state out
    int* __restrict__ arrive)         // [ENBLK*16], pre-zeroed
{
    const int b    = blockIdx.x;
    const int tid  = threadIdx.x;
    const int w    = tid >> 6;        // wave 0..15
    const int lane = tid & 63;
    const int j0   = b * EJPB;
    const int g    = w >> 2;          // gate 0..3
    const int e0   = (w & 3) * 4;     // element sub-offset 0,4,8,12

    __shared__ float bufH[HD];
    __shared__ float g_s[64];         // [gate][elem] = g*16+e
    __shared__ float c_s[EJPB];

    // register-resident W_hh slice: wave w -> gate g, elems e0..e0+3
    float wreg[4][16];
#pragma unroll
    for (int d = 0; d < 4; ++d) {
        const int grow = g * HD + j0 + e0 + d;
        const float* src = Whh + (size_t)grow * HD + lane;
#pragma unroll
        for (int q = 0; q < 16; ++q) wreg[d][q] = src[q * 64];
    }

    if (tid < EJPB) c_s[tid] = 0.f;

    for (int t = 0; t < TLEN; ++t) {
        // wait until all blocks have published row t (row 0 pre-zeroed, flags start 0)
        if (w == 0) {
            for (;;) {
                int v = __hip_atomic_load(arrive + lane * 16, __ATOMIC_RELAXED, DEV_SCOPE);
                if (__all(v >= t)) break;
                __builtin_amdgcn_s_sleep(2);
            }
        }
        __syncthreads();

        // gather h_t (1 element per thread, device-scope = always fresh)
        bufH[tid] = __hip_atomic_load(hs + (size_t)t * HD + tid, __ATOMIC_RELAXED, DEV_SCOPE);
        __syncthreads();

        // 4 register-resident dot products per wave
        float acc[4];
#pragma unroll
        for (int d = 0; d < 4; ++d) {
            float a = 0.f;
#pragma unroll
            for (int q = 0; q < 16; ++q)
                a = fmaf(wreg[d][q], bufH[q * 64 + lane], a);
#pragma unroll
            for (int off = 32; off > 0; off >>= 1) a += __shfl_down(a, off);
            acc[d] = a;
        }
        if (lane == 0) {
#pragma unroll
            for (int d = 0; d < 4; ++d) g_s[g * 16 + e0 + d] = acc[d];
        }
        __syncthreads();

        // gate math + publish h_{t+1} slice (wave 0, lanes 0..15)
        if (tid < EJPB) {
            const int j = j0 + tid;
            const float* gx = Gx + (size_t)t * G4H;
            const float gi = g_s[tid]      + gx[0 * HD + j];
            const float gf = g_s[16 + tid] + gx[1 * HD + j];
            const float gg = g_s[32 + tid] + gx[2 * HD + j];
            const float go = g_s[48 + tid] + gx[3 * HD + j];
            const float i_ = 1.f / (1.f + expf(-gi));
            const float f_ = 1.f / (1.f + expf(-gf));
            const float o_ = 1.f / (1.f + expf(-go));
            const float g2 = tanhf(gg);
            const float c2 = f_ * c_s[tid] + i_ * g2;
            c_s[tid] = c2;
            const float hv = o_ * tanhf(c2);
            __hip_atomic_store(hs + (size_t)(t + 1) * HD + j, hv, __ATOMIC_RELAXED, DEV_SCOPE);
        }
        // wave 0: ensure h stores hit the coherence point, then raise flag
        asm volatile("s_waitcnt vmcnt(0)" ::: "memory");
        if (tid == 0)
            __hip_atomic_store(arrive + b * 16, t + 1, __ATOMIC_RELAXED, DEV_SCOPE);
    }

    if (tid < EJPB) ct[j0 + tid] = c_s[tid];   // kernel boundary flushes
}

// ============================================================
// Kernel 3: cooperative greedy attention decoder (unchanged structure).
// ============================================================
__global__ __launch_bounds__(256) void dec_kernel(
    const float* __restrict__ embT,
    const float* __restrict__ Wdih,
    const float* __restrict__ Wdhh,
    const float* __restrict__ bdv,
    const float* __restrict__ Wattn,
    const float* __restrict__ battn,
    const float* __restrict__ Wout,
    const float* __restrict__ bout,
    float* __restrict__ wsf,
    float* __restrict__ out)
{
    cg::grid_group grid = cg::this_grid();
    const int b    = blockIdx.x;
    const int tid  = threadIdx.x;
    const int w    = tid >> 6;
    const int lane = tid & 63;
    const int j0   = b * JPB;

    float* hs   = wsf + OFF_HS;
    float* hd   = wsf + OFF_HD;
    float* sc   = wsf + OFF_SC;
    float* pd   = wsf + OFF_PD;
    float* dctx = wsf + OFF_DC;
    float* htn  = wsf + OFF_HTN;
    float* bmv  = wsf + OFF_BMV;
    float* ctw  = wsf + OFF_CT;
    int*   bmi  = (int*)(wsf + OFF_INT);
    int*   state = bmi + NBLK;

    __shared__ float bufAB[2 * HD];
    __shared__ float g_s[4 * JPB];
    __shared__ float c_s[JPB];
    __shared__ float red[NTHR];
    __shared__ int   redi[NTHR];
    __shared__ float wt_s[TPB];

    if (tid < JPB) {
        c_s[tid] = ctw[j0 + tid];
        hd[j0 + tid] = hs[(size_t)TLEN * HD + j0 + tid];
    }
    if (b == 0 && tid == 0) { state[0] = BOS_ID; state[1] = 0; }
    grid.sync();

    for (int s = 0; s < NSTEP; ++s) {
        float* hcur = hd + (s & 1) * HD;
        float* hnxt = hd + ((s + 1) & 1) * HD;

        // ---- ph1: LSTM gates ----
        {
            const int widv = state[0];
            const float* x = embT + (size_t)widv * HD;
            for (int i = tid; i < HD; i += NTHR) {
                bufAB[i] = x[i];
                bufAB[HD + i] = hcur[i];
            }
            __syncthreads();
#pragma unroll
            for (int d = 0; d < 4; ++d) {
                const int grow = w * HD + j0 + d;
                const float* wi = Wdih + (size_t)grow * HD;
                const float* wh = Wdhh + (size_t)grow * HD;
                float a = 0.f;
                for (int k = lane; k < HD; k += 64)
                    a = fmaf(wi[k], bufAB[k], fmaf(wh[k], bufAB[HD + k], a));
#pragma unroll
                for (int off = 32; off > 0; off >>= 1) a += __shfl_down(a, off);
                if (lane == 0) g_s[w * 4 + d] = a;
            }
            __syncthreads();
            if (tid < JPB) {
                const int j = j0 + tid;
                const float gi = g_s[0 * 4 + tid] + bdv[0 * HD + j];
                const float gf = g_s[1 * 4 + tid] + bdv[1 * HD + j];
                const float gg = g_s[2 * 4 + tid] + bdv[2 * HD + j];
                const float go = g_s[3 * 4 + tid] + bdv[3 * HD + j];
                const float i_ = 1.f / (1.f + expf(-gi));
                const float f_ = 1.f / (1.f + expf(-gf));
                const float o_ = 1.f / (1.f + expf(-go));
                const float g2 = tanhf(gg);
                const float c2 = f_ * c_s[tid] + i_ * g2;
                c_s[tid] = c2;
                hnxt[j] = o_ * tanhf(c2);
            }
        }
        grid.sync();

        // ---- ph2: attention scores ----
        for (int i = tid; i < HD; i += NTHR) bufAB[i] = hnxt[i];
        __syncthreads();
#pragma unroll
        for (int d = 0; d < 2; ++d) {
            const int t = b * TPB + w * 2 + d;
            const float* hrow = hs + (size_t)(t + 1) * HD;
            float a = 0.f;
            for (int k = lane; k < HD; k += 64) a = fmaf(hrow[k], bufAB[k], a);
#pragma unroll
            for (int off = 32; off > 0; off >>= 1) a += __shfl_down(a, off);
            if (lane == 0) sc[t] = a;
        }
        grid.sync();

        // ---- ph3: softmax stats + partial context ----
        {
            float lm = -INFINITY;
            for (int t = tid; t < TLEN; t += NTHR) lm = fmaxf(lm, sc[t]);
            red[tid] = lm; __syncthreads();
            for (int s2 = NTHR / 2; s2 > 0; s2 >>= 1) {
                if (tid < s2) red[tid] = fmaxf(red[tid], red[tid + s2]);
                __syncthreads();
            }
            const float m = red[0]; __syncthreads();
            float lz = 0.f;
            for (int t = tid; t < TLEN; t += NTHR) lz += expf(sc[t] - m);
            red[tid] = lz; __syncthreads();
            for (int s2 = NTHR / 2; s2 > 0; s2 >>= 1) {
                if (tid < s2) red[tid] += red[tid + s2];
                __syncthreads();
            }
            const float Zi = 1.f / red[0]; __syncthreads();
            if (tid < TPB) wt_s[tid] = expf(sc[b * TPB + tid] - m) * Zi;
            __syncthreads();
#pragma unroll
            for (int jj = 0; jj < HD / NTHR; ++jj) {
                const int j = tid + jj * NTHR;
                float a = 0.f;
#pragma unroll
                for (int d = 0; d < TPB; ++d)
                    a = fmaf(wt_s[d], hs[(size_t)(b * TPB + d + 1) * HD + j], a);
                pd[(size_t)b * HD + j] = a;
            }
        }
        grid.sync();

        // ---- ph4: reduce partial contexts ----
        {
            const int j = j0 + w;
            float a = 0.f;
#pragma unroll
            for (int q = 0; q < NBLK / 64; ++q)
                a += pd[(size_t)(lane + q * 64) * HD + j];
#pragma unroll
            for (int off = 32; off > 0; off >>= 1) a += __shfl_down(a, off);
            if (lane == 0) dctx[j] = a;
        }
        grid.sync();

        // ---- ph5: ht_new ----
        for (int i = tid; i < HD; i += NTHR) {
            bufAB[i] = dctx[i];
            bufAB[HD + i] = hnxt[i];
        }
        __syncthreads();
        {
            const int j = j0 + w;
            const float* wr = Wattn + (size_t)j * (2 * HD);
            float a = 0.f;
            for (int k = lane; k < 2 * HD; k += 64) a = fmaf(wr[k], bufAB[k], a);
#pragma unroll
            for (int off = 32; off > 0; off >>= 1) a += __shfl_down(a, off);
            if (lane == 0) htn[j] = tanhf(a + battn[j]);
        }
        grid.sync();

        // ---- ph6: logits + block argmax ----
        for (int i = tid; i < HD; i += NTHR) bufAB[i] = htn[i];
        __syncthreads();
        {
            const int donev = state[1];
            const int r0 = b * RPB;
            float bv = -INFINITY; int bi = 0x7fffffff;
            for (int r = r0 + w; r < r0 + RPB; r += 4) {
                const float* wr = Wout + (size_t)r * HD;
                float a = 0.f;
                for (int k = lane; k < HD; k += 64) a = fmaf(wr[k], bufAB[k], a);
#pragma unroll
                for (int off = 32; off > 0; off >>= 1) a += __shfl_down(a, off);
                if (lane == 0) {
                    a += bout[r];
                    out[NSTEP + (size_t)s * VOUTN + r] = donev ? 0.f : a;
                    if (a > bv || (a == bv && r < bi)) { bv = a; bi = r; }
                }
            }
            if (lane == 0) { red[w] = bv; redi[w] = bi; }
            __syncthreads();
            if (tid == 0) {
                float v = red[0]; int ii = redi[0];
#pragma unroll
                for (int q = 1; q < 4; ++q)
                    if (red[q] > v || (red[q] == v && redi[q] < ii)) { v = red[q]; ii = redi[q]; }
                bmv[b] = v; bmi[b] = ii;
            }
        }
        grid.sync();

        // ---- ph7: global argmax + state ----
        if (b == 0) {
            red[tid] = bmv[tid]; redi[tid] = bmi[tid];
            __syncthreads();
            for (int s2 = NTHR / 2; s2 > 0; s2 >>= 1) {
                if (tid < s2) {
                    if (red[tid + s2] > red[tid] ||
                        (red[tid + s2] == red[tid] && redi[tid + s2] < redi[tid])) {
                        red[tid] = red[tid + s2]; redi[tid] = redi[tid + s2];
                    }
                }
                __syncthreads();
            }
            if (tid == 0) {
                const int nid = redi[0];
                const int olddone = state[1];
                out[s] = olddone ? 0.f : (float)nid;
                state[0] = nid;
                state[1] = olddone | (nid == EOS_ID);
            }
        }
        grid.sync();
    }
}

extern "C" void kernel_launch(void* const* d_in, const int* in_sizes, int n_in,
                              void* d_out, int out_size, void* d_ws, size_t ws_size,
                              hipStream_t stream) {
    (void)in_sizes; (void)n_in; (void)out_size; (void)ws_size;
    const int*   src_ids = (const int*)  d_in[0];
    const float* emb_in  = (const float*)d_in[1];
    const float* We_ih   = (const float*)d_in[2];
    const float* We_hh   = (const float*)d_in[3];
    const float* be      = (const float*)d_in[4];
    const float* emb_tgt = (const float*)d_in[5];
    const float* Wd_ih   = (const float*)d_in[6];
    const float* Wd_hh   = (const float*)d_in[7];
    const float* bd      = (const float*)d_in[8];
    const float* W_attn  = (const float*)d_in[9];
    const float* b_attn  = (const float*)d_in[10];
    const float* W_out   = (const float*)d_in[11];
    const float* b_out   = (const float*)d_in[12];

    float* outp = (float*)d_out;
    float* wsf  = (float*)d_ws;

    // deterministic init: h_0 row and encoder arrive flags
    hipMemsetAsync(wsf + OFF_HS, 0, HD * sizeof(float), stream);
    hipMemsetAsync(wsf + OFF_ARR, 0, ENBLK * 16 * sizeof(int), stream);

    // Phase 1: Gx = X @ We_ih^T + be
    dim3 g1(TLEN / 128, G4H / 128);
    gx_gemm<<<g1, 256, 0, stream>>>(src_ids, emb_in, We_ih, be, wsf + OFF_GX);

    // Phase 2: encoder (cooperative for co-residency; custom barrier inside)
    {
        const float* a_Whh = We_hh;
        const float* a_Gx  = wsf + OFF_GX;
        float* a_hs  = wsf + OFF_HS;
        float* a_ct  = wsf + OFF_CT;
        int*   a_arr = (int*)(wsf + OFF_ARR);
        void* args[] = { &a_Whh, &a_Gx, &a_hs, &a_ct, &a_arr };
        hipLaunchCooperativeKernel(reinterpret_cast<void*>(enc_kernel),
                                   dim3(ENBLK), dim3(ENTHR), args, 0, stream);
    }

    // Phase 3: decoder (cooperative, grid.sync)
    {
        const float* a_embT = emb_tgt;
        const float* a_Wdih = Wd_ih;  const float* a_Wdhh = Wd_hh;
        const float* a_bd   = bd;     const float* a_Wat  = W_attn;
        const float* a_bat  = b_attn; const float* a_Wout = W_out;
        const float* a_bout = b_out;
        float* a_ws = wsf; float* a_out = outp;
        void* args[] = { &a_embT, &a_Wdih, &a_Wdhh, &a_bd,
                         &a_Wat, &a_bat, &a_Wout, &a_bout, &a_ws, &a_out };
        hipLaunchCooperativeKernel(reinterpret_cast<void*>(dec_kernel),
                                   dim3(NBLK), dim3(NTHR), args, 0, stream);
    }
}

// Round 5
// 11446.285 us; speedup vs baseline: 6.9234x; 2.4201x over previous
//
#include <hip/hip_runtime.h>
#include <math.h>

#define HD     1024
#define TLEN   2048
#define G4H    4096
#define VOUTN  32000
#define NSTEP  50
#define BOS_ID 1
#define EOS_ID 2

// ---- decoder grids ----
#define NBLK 256
#define NTHR 256
#define JPB  (HD / NBLK)     // 4
#define TPB  (TLEN / NBLK)   // 8
#define RPB  (VOUTN / NBLK)  // 125

// ---- encoder grid ----
#define ENBLK 64
#define ENTHR 1024
#define EJPB  (HD / ENBLK)   // 16

// ---- workspace layout (float offsets) ----
#define OFF_GX   ((size_t)0)                          // [TLEN][4H]
#define OFF_HS   (OFF_GX + (size_t)TLEN * G4H)        // [TLEN+1][HD]
#define OFF_HD   (OFF_HS + (size_t)(TLEN + 1) * HD)   // [2][HD] decoder h dbuf
#define OFF_SC   (OFF_HD + 2 * HD)                    // [TLEN] scores
#define OFF_DC   (OFF_SC + TLEN)                      // [HD] context
#define OFF_HTN  (OFF_DC + HD)                        // [HD] ht_new
#define OFF_BMV  (OFF_HTN + HD)                       // [NBLK] block argmax val
#define OFF_BMI  (OFF_BMV + NBLK)                     // [NBLK] block argmax idx (int)
#define OFF_CT   (OFF_BMI + NBLK)                     // [HD] decoder cell state
#define OFF_ST   (OFF_CT + HD)                        // [NSTEP+1] packed state (int)
#define OFF_ARR  (OFF_ST + NSTEP + 1 + 13)            // enc flags [ENBLK*16] (int)

#define DEV_SCOPE __HIP_MEMORY_SCOPE_AGENT

__device__ __forceinline__ float dload(const float* p) {
    return __hip_atomic_load(p, __ATOMIC_RELAXED, DEV_SCOPE);
}
__device__ __forceinline__ void dstore(float* p, float v) {
    __hip_atomic_store(p, v, __ATOMIC_RELAXED, DEV_SCOPE);
}
__device__ __forceinline__ int diload(const int* p) {
    return __hip_atomic_load(p, __ATOMIC_RELAXED, DEV_SCOPE);
}
__device__ __forceinline__ void distore(int* p, int v) {
    __hip_atomic_store(p, v, __ATOMIC_RELAXED, DEV_SCOPE);
}

// ============================================================
// Kernel 1: Gx[t][r] = be[r] + sum_k emb[src_ids[t]][k] * We_ih[r][k]
// (unchanged — passed R1/R2)
// ============================================================
__global__ __launch_bounds__(256) void gx_gemm(
    const int* __restrict__ src_ids,
    const float* __restrict__ emb,
    const float* __restrict__ Wih,
    const float* __restrict__ be,
    float* __restrict__ Gx)
{
    __shared__ float As[128][17];
    __shared__ float Bs[128][17];
    __shared__ int   sid[128];

    const int tid = threadIdx.x;
    const int t0 = blockIdx.x * 128;
    const int r0 = blockIdx.y * 128;

    if (tid < 128) sid[tid] = src_ids[t0 + tid];
    __syncthreads();

    const int tx = tid & 15;
    const int ty = tid >> 4;
    const int lrow = tid >> 1;
    const int lk   = (tid & 1) * 8;

    float acc[8][8];
#pragma unroll
    for (int i = 0; i < 8; ++i)
#pragma unroll
        for (int j = 0; j < 8; ++j) acc[i][j] = 0.f;

    for (int k0 = 0; k0 < HD; k0 += 16) {
        {
            const float* xa = emb + (size_t)sid[lrow] * HD + k0 + lk;
            float4 v0 = *(const float4*)xa;
            float4 v1 = *(const float4*)(xa + 4);
            As[lrow][lk + 0] = v0.x; As[lrow][lk + 1] = v0.y;
            As[lrow][lk + 2] = v0.z; As[lrow][lk + 3] = v0.w;
            As[lrow][lk + 4] = v1.x; As[lrow][lk + 5] = v1.y;
            As[lrow][lk + 6] = v1.z; As[lrow][lk + 7] = v1.w;
            const float* wb = Wih + (size_t)(r0 + lrow) * HD + k0 + lk;
            float4 w0 = *(const float4*)wb;
            float4 w1 = *(const float4*)(wb + 4);
            Bs[lrow][lk + 0] = w0.x; Bs[lrow][lk + 1] = w0.y;
            Bs[lrow][lk + 2] = w0.z; Bs[lrow][lk + 3] = w0.w;
            Bs[lrow][lk + 4] = w1.x; Bs[lrow][lk + 5] = w1.y;
            Bs[lrow][lk + 6] = w1.z; Bs[lrow][lk + 7] = w1.w;
        }
        __syncthreads();
#pragma unroll
        for (int kk = 0; kk < 16; ++kk) {
            float a[8], bv[8];
#pragma unroll
            for (int i = 0; i < 8; ++i) a[i]  = As[ty * 8 + i][kk];
#pragma unroll
            for (int j = 0; j < 8; ++j) bv[j] = Bs[tx * 8 + j][kk];
#pragma unroll
            for (int i = 0; i < 8; ++i)
#pragma unroll
                for (int j = 0; j < 8; ++j)
                    acc[i][j] = fmaf(a[i], bv[j], acc[i][j]);
        }
        __syncthreads();
    }

    float bev[8];
#pragma unroll
    for (int j = 0; j < 8; ++j) bev[j] = be[r0 + tx * 8 + j];
#pragma unroll
    for (int i = 0; i < 8; ++i) {
        const int t = t0 + ty * 8 + i;
        float* dst = Gx + (size_t)t * G4H + r0 + tx * 8;
#pragma unroll
        for (int j = 0; j < 8; ++j) dst[j] = acc[i][j] + bev[j];
    }
}

// ============================================================
// Kernel 2: encoder recurrence (flag-barrier) — proven in R2.
// Tail additionally seeds decoder state: cdec, hd[0]=hT, st[0]=BOS.
// ============================================================
__global__ __launch_bounds__(1024, 4) void enc_kernel(
    const float* __restrict__ Whh,
    const float* __restrict__ Gx,
    float* __restrict__ wsf,
    int* __restrict__ arrive)
{
    float* hs   = wsf + OFF_HS;
    float* hd   = wsf + OFF_HD;
    float* cdec = wsf + OFF_CT;
    int*   st   = (int*)(wsf + OFF_ST);

    const int b    = blockIdx.x;
    const int tid  = threadIdx.x;
    const int w    = tid >> 6;
    const int lane = tid & 63;
    const int j0   = b * EJPB;
    const int g    = w >> 2;
    const int e0   = (w & 3) * 4;

    __shared__ float bufH[HD];
    __shared__ float g_s[64];
    __shared__ float c_s[EJPB];

    float wreg[4][16];
#pragma unroll
    for (int d = 0; d < 4; ++d) {
        const int grow = g * HD + j0 + e0 + d;
        const float* src = Whh + (size_t)grow * HD + lane;
#pragma unroll
        for (int q = 0; q < 16; ++q) wreg[d][q] = src[q * 64];
    }

    if (tid < EJPB) c_s[tid] = 0.f;

    for (int t = 0; t < TLEN; ++t) {
        if (w == 0) {
            for (;;) {
                int v = diload(arrive + lane * 16);
                if (__all(v >= t)) break;
                __builtin_amdgcn_s_sleep(1);
            }
        }
        __syncthreads();

        bufH[tid] = dload(hs + (size_t)t * HD + tid);
        __syncthreads();

        float acc[4];
#pragma unroll
        for (int d = 0; d < 4; ++d) {
            float a = 0.f;
#pragma unroll
            for (int q = 0; q < 16; ++q)
                a = fmaf(wreg[d][q], bufH[q * 64 + lane], a);
#pragma unroll
            for (int off = 32; off > 0; off >>= 1) a += __shfl_down(a, off);
            acc[d] = a;
        }
        if (lane == 0) {
#pragma unroll
            for (int d = 0; d < 4; ++d) g_s[g * 16 + e0 + d] = acc[d];
        }
        __syncthreads();

        if (tid < EJPB) {
            const int j = j0 + tid;
            const float* gx = Gx + (size_t)t * G4H;
            const float gi = g_s[tid]      + gx[0 * HD + j];
            const float gf = g_s[16 + tid] + gx[1 * HD + j];
            const float gg = g_s[32 + tid] + gx[2 * HD + j];
            const float go = g_s[48 + tid] + gx[3 * HD + j];
            const float i_ = 1.f / (1.f + expf(-gi));
            const float f_ = 1.f / (1.f + expf(-gf));
            const float o_ = 1.f / (1.f + expf(-go));
            const float g2 = tanhf(gg);
            const float c2 = f_ * c_s[tid] + i_ * g2;
            c_s[tid] = c2;
            dstore(hs + (size_t)(t + 1) * HD + j, o_ * tanhf(c2));
        }
        asm volatile("s_waitcnt vmcnt(0)" ::: "memory");
        if (tid == 0) distore(arrive + b * 16, t + 1);
    }

    // seed decoder state (kernel boundary publishes)
    if (tid < EJPB) {
        cdec[j0 + tid] = c_s[tid];
        hd[j0 + tid]   = hs[(size_t)TLEN * HD + j0 + tid];
    }
    if (b == 0 && tid == 0) st[0] = BOS_ID;   // done=0, wid=BOS
}

// ============================================================
// Decoder step kernels — ordinary launches; kernel boundary = global sync.
// st[s] = (done<<16) | wid  (state ENTERING step s).
// ============================================================

// K1: LSTM gates -> hnxt, cdec update
__global__ __launch_bounds__(256) void k_gates(
    const float* __restrict__ embT,
    const float* __restrict__ Wdih,
    const float* __restrict__ Wdhh,
    const float* __restrict__ bdv,
    float* __restrict__ wsf, int s)
{
    float* hd   = wsf + OFF_HD;
    float* cdec = wsf + OFF_CT;
    const int* st = (const int*)(wsf + OFF_ST);

    const int b    = blockIdx.x;
    const int tid  = threadIdx.x;
    const int w    = tid >> 6;
    const int lane = tid & 63;
    const int j0   = b * JPB;

    const float* hcur = hd + (s & 1) * HD;
    float*       hnxt = hd + ((s + 1) & 1) * HD;

    __shared__ float bufAB[2 * HD];
    __shared__ float g_s[4 * JPB];
    const float4* buf4 = (const float4*)bufAB;

    const int widv = st[s] & 0xFFFF;
    const float* x = embT + (size_t)widv * HD;
    for (int i = tid; i < HD; i += NTHR) {
        bufAB[i]      = x[i];
        bufAB[HD + i] = hcur[i];
    }
    __syncthreads();

#pragma unroll
    for (int d = 0; d < 4; ++d) {
        const int grow = w * HD + j0 + d;
        const float4* wi4 = (const float4*)(Wdih + (size_t)grow * HD);
        const float4* wh4 = (const float4*)(Wdhh + (size_t)grow * HD);
        float4 a4 = make_float4(0.f, 0.f, 0.f, 0.f);
#pragma unroll
        for (int q = 0; q < 4; ++q) {
            float4 wv = wi4[q * 64 + lane], xv = buf4[q * 64 + lane];
            a4.x = fmaf(wv.x, xv.x, a4.x); a4.y = fmaf(wv.y, xv.y, a4.y);
            a4.z = fmaf(wv.z, xv.z, a4.z); a4.w = fmaf(wv.w, xv.w, a4.w);
            float4 wv2 = wh4[q * 64 + lane], hv = buf4[256 + q * 64 + lane];
            a4.x = fmaf(wv2.x, hv.x, a4.x); a4.y = fmaf(wv2.y, hv.y, a4.y);
            a4.z = fmaf(wv2.z, hv.z, a4.z); a4.w = fmaf(wv2.w, hv.w, a4.w);
        }
        float a = (a4.x + a4.y) + (a4.z + a4.w);
#pragma unroll
        for (int off = 32; off > 0; off >>= 1) a += __shfl_down(a, off);
        if (lane == 0) g_s[w * 4 + d] = a;
    }
    __syncthreads();

    if (tid < JPB) {
        const int j = j0 + tid;
        const float gi = g_s[0 * 4 + tid] + bdv[0 * HD + j];
        const float gf = g_s[1 * 4 + tid] + bdv[1 * HD + j];
        const float gg = g_s[2 * 4 + tid] + bdv[2 * HD + j];
        const float go = g_s[3 * 4 + tid] + bdv[3 * HD + j];
        const float i_ = 1.f / (1.f + expf(-gi));
        const float f_ = 1.f / (1.f + expf(-gf));
        const float o_ = 1.f / (1.f + expf(-go));
        const float g2 = tanhf(gg);
        const float c2 = f_ * cdec[j] + i_ * g2;
        cdec[j] = c2;
        hnxt[j] = o_ * tanhf(c2);
    }
}

// K2: attention scores sc[t] = hs[t+1] . hnxt
__global__ __launch_bounds__(256) void k_scores(float* __restrict__ wsf, int s)
{
    const float* hs = wsf + OFF_HS;
    const float* hnxt = wsf + OFF_HD + (size_t)((s + 1) & 1) * HD;
    float* sc = wsf + OFF_SC;

    const int b    = blockIdx.x;
    const int tid  = threadIdx.x;
    const int w    = tid >> 6;
    const int lane = tid & 63;

    __shared__ float bufH[HD];
    const float4* buf4 = (const float4*)bufH;
    for (int i = tid; i < HD; i += NTHR) bufH[i] = hnxt[i];
    __syncthreads();

#pragma unroll
    for (int d = 0; d < 2; ++d) {
        const int t = b * TPB + w * 2 + d;
        const float4* hr4 = (const float4*)(hs + (size_t)(t + 1) * HD);
        float4 a4 = make_float4(0.f, 0.f, 0.f, 0.f);
#pragma unroll
        for (int q = 0; q < 4; ++q) {
            float4 hv = hr4[q * 64 + lane], bv = buf4[q * 64 + lane];
            a4.x = fmaf(hv.x, bv.x, a4.x); a4.y = fmaf(hv.y, bv.y, a4.y);
            a4.z = fmaf(hv.z, bv.z, a4.z); a4.w = fmaf(hv.w, bv.w, a4.w);
        }
        float a = (a4.x + a4.y) + (a4.z + a4.w);
#pragma unroll
        for (int off = 32; off > 0; off >>= 1) a += __shfl_down(a, off);
        if (lane == 0) sc[t] = a;
    }
}

// K3: block-redundant softmax over sc + context slice dctx[j0..j0+3]
__global__ __launch_bounds__(256) void k_ctx(float* __restrict__ wsf)
{
    const float* hs = wsf + OFF_HS;
    const float* sc = wsf + OFF_SC;
    float* dctx = wsf + OFF_DC;

    const int b    = blockIdx.x;
    const int tid  = threadIdx.x;
    const int w    = tid >> 6;
    const int lane = tid & 63;
    const int j0   = b * JPB;

    __shared__ float sc_s[TLEN];
    __shared__ float red[NTHR];

    for (int t = tid; t < TLEN; t += NTHR) sc_s[t] = sc[t];
    __syncthreads();

    float lm = -INFINITY;
    for (int t = tid; t < TLEN; t += NTHR) lm = fmaxf(lm, sc_s[t]);
    red[tid] = lm; __syncthreads();
    for (int s2 = NTHR / 2; s2 > 0; s2 >>= 1) {
        if (tid < s2) red[tid] = fmaxf(red[tid], red[tid + s2]);
        __syncthreads();
    }
    const float m = red[0]; __syncthreads();
    float lz = 0.f;
    for (int t = tid; t < TLEN; t += NTHR) lz += expf(sc_s[t] - m);
    red[tid] = lz; __syncthreads();
    for (int s2 = NTHR / 2; s2 > 0; s2 >>= 1) {
        if (tid < s2) red[tid] += red[tid + s2];
        __syncthreads();
    }
    const float Zi = 1.f / red[0]; __syncthreads();

    // wave w owns output element j0+w; lanes sum over t
    const int j = j0 + w;
    float a = 0.f;
#pragma unroll
    for (int it = 0; it < TLEN / 64; ++it) {
        const int t = lane + it * 64;
        const float wt = expf(sc_s[t] - m) * Zi;
        a = fmaf(wt, hs[(size_t)(t + 1) * HD + j], a);
    }
#pragma unroll
    for (int off = 32; off > 0; off >>= 1) a += __shfl_down(a, off);
    if (lane == 0) dctx[j] = a;
}

// K4: ht_new = tanh(W_attn @ [d; ht] + b_attn)
__global__ __launch_bounds__(256) void k_attn(
    const float* __restrict__ Wattn,
    const float* __restrict__ battn,
    float* __restrict__ wsf, int s)
{
    const float* dctx = wsf + OFF_DC;
    const float* hnxt = wsf + OFF_HD + (size_t)((s + 1) & 1) * HD;
    float* htn = wsf + OFF_HTN;

    const int b    = blockIdx.x;
    const int tid  = threadIdx.x;
    const int w    = tid >> 6;
    const int lane = tid & 63;
    const int j0   = b * JPB;

    __shared__ float bufAB[2 * HD];
    const float4* buf4 = (const float4*)bufAB;
    for (int i = tid; i < HD; i += NTHR) {
        bufAB[i]      = dctx[i];
        bufAB[HD + i] = hnxt[i];
    }
    __syncthreads();

    const int j = j0 + w;
    const float4* wr4 = (const float4*)(Wattn + (size_t)j * (2 * HD));
    float4 a4 = make_float4(0.f, 0.f, 0.f, 0.f);
#pragma unroll
    for (int q = 0; q < 8; ++q) {
        float4 wv = wr4[q * 64 + lane], bv = buf4[q * 64 + lane];
        a4.x = fmaf(wv.x, bv.x, a4.x); a4.y = fmaf(wv.y, bv.y, a4.y);
        a4.z = fmaf(wv.z, bv.z, a4.z); a4.w = fmaf(wv.w, bv.w, a4.w);
    }
    float a = (a4.x + a4.y) + (a4.z + a4.w);
#pragma unroll
    for (int off = 32; off > 0; off >>= 1) a += __shfl_down(a, off);
    if (lane == 0) htn[j] = tanhf(a + battn[j]);
}

// K5: logits = W_out @ ht_new + b_out ; masked write ; per-block argmax
__global__ __launch_bounds__(256) void k_logits(
    const float* __restrict__ Wout,
    const float* __restrict__ bout,
    float* __restrict__ wsf,
    float* __restrict__ out, int s)
{
    const float* htn = wsf + OFF_HTN;
    float* bmv = wsf + OFF_BMV;
    int*   bmi = (int*)(wsf + OFF_BMI);
    const int* st = (const int*)(wsf + OFF_ST);

    const int b    = blockIdx.x;
    const int tid  = threadIdx.x;
    const int w    = tid >> 6;
    const int lane = tid & 63;

    __shared__ float bufH[HD];
    __shared__ float red[4];
    __shared__ int   redi[4];
    const float4* buf4 = (const float4*)bufH;

    const int donev = (st[s] >> 16) & 1;
    for (int i = tid; i < HD; i += NTHR) bufH[i] = htn[i];
    __syncthreads();

    const int r0b = b * RPB;
    const int rbeg = r0b + w * 32;
    const int rend = min(r0b + RPB, rbeg + 32);
    float bv = -INFINITY; int bi = 0x7fffffff;
    for (int r = rbeg; r < rend; r += 2) {
        const int two = (r + 1 < rend);
        const float4* w0 = (const float4*)(Wout + (size_t)r * HD);
        const float4* w1 = (const float4*)(Wout + (size_t)(r + two) * HD);
        float4 a04 = make_float4(0.f, 0.f, 0.f, 0.f);
        float4 a14 = make_float4(0.f, 0.f, 0.f, 0.f);
#pragma unroll
        for (int q = 0; q < 4; ++q) {
            float4 hv = buf4[q * 64 + lane];
            float4 x0 = w0[q * 64 + lane];
            float4 x1 = w1[q * 64 + lane];
            a04.x = fmaf(x0.x, hv.x, a04.x); a04.y = fmaf(x0.y, hv.y, a04.y);
            a04.z = fmaf(x0.z, hv.z, a04.z); a04.w = fmaf(x0.w, hv.w, a04.w);
            a14.x = fmaf(x1.x, hv.x, a14.x); a14.y = fmaf(x1.y, hv.y, a14.y);
            a14.z = fmaf(x1.z, hv.z, a14.z); a14.w = fmaf(x1.w, hv.w, a14.w);
        }
        float a0 = (a04.x + a04.y) + (a04.z + a04.w);
        float a1 = (a14.x + a14.y) + (a14.z + a14.w);
#pragma unroll
        for (int off = 32; off > 0; off >>= 1) {
            a0 += __shfl_down(a0, off);
            a1 += __shfl_down(a1, off);
        }
        if (lane == 0) {
            a0 += bout[r];
            out[NSTEP + (size_t)s * VOUTN + r] = donev ? 0.f : a0;
            if (a0 > bv) { bv = a0; bi = r; }
            if (two) {
                a1 += bout[r + 1];
                out[NSTEP + (size_t)s * VOUTN + r + 1] = donev ? 0.f : a1;
                if (a1 > bv) { bv = a1; bi = r + 1; }
            }
        }
    }
    if (lane == 0) { red[w] = bv; redi[w] = bi; }
    __syncthreads();
    if (tid == 0) {
        float v = red[0]; int ii = redi[0];
#pragma unroll
        for (int q = 1; q < 4; ++q)
            if (red[q] > v || (red[q] == v && redi[q] < ii)) { v = red[q]; ii = redi[q]; }
        bmv[b] = v; bmi[b] = ii;
    }
}

// K6: global argmax (first index on ties), token + next state
__global__ __launch_bounds__(256) void k_amax(
    float* __restrict__ wsf, float* __restrict__ out, int s)
{
    const float* bmv = wsf + OFF_BMV;
    const int*   bmi = (const int*)(wsf + OFF_BMI);
    int* st = (int*)(wsf + OFF_ST);

    const int tid = threadIdx.x;
    __shared__ float red[NTHR];
    __shared__ int   redi[NTHR];

    red[tid] = bmv[tid]; redi[tid] = bmi[tid];
    __syncthreads();
    for (int s2 = NTHR / 2; s2 > 0; s2 >>= 1) {
        if (tid < s2) {
            if (red[tid + s2] > red[tid] ||
                (red[tid + s2] == red[tid] && redi[tid + s2] < redi[tid])) {
                red[tid] = red[tid + s2]; redi[tid] = redi[tid + s2];
            }
        }
        __syncthreads();
    }
    if (tid == 0) {
        const int nid = redi[0];
        const int donev = (st[s] >> 16) & 1;
        out[s] = donev ? 0.f : (float)nid;
        const int done2 = donev | (nid == EOS_ID);
        st[s + 1] = (done2 << 16) | nid;
    }
}

extern "C" void kernel_launch(void* const* d_in, const int* in_sizes, int n_in,
                              void* d_out, int out_size, void* d_ws, size_t ws_size,
                              hipStream_t stream) {
    (void)in_sizes; (void)n_in; (void)out_size; (void)ws_size;
    const int*   src_ids = (const int*)  d_in[0];
    const float* emb_in  = (const float*)d_in[1];
    const float* We_ih   = (const float*)d_in[2];
    const float* We_hh   = (const float*)d_in[3];
    const float* be      = (const float*)d_in[4];
    const float* emb_tgt = (const float*)d_in[5];
    const float* Wd_ih   = (const float*)d_in[6];
    const float* Wd_hh   = (const float*)d_in[7];
    const float* bd      = (const float*)d_in[8];
    const float* W_attn  = (const float*)d_in[9];
    const float* b_attn  = (const float*)d_in[10];
    const float* W_out   = (const float*)d_in[11];
    const float* b_out   = (const float*)d_in[12];

    float* outp = (float*)d_out;
    float* wsf  = (float*)d_ws;

    // deterministic init: h0 row + encoder flags
    hipMemsetAsync(wsf + OFF_HS, 0, HD * sizeof(float), stream);
    hipMemsetAsync(wsf + OFF_ARR, 0, ENBLK * 16 * sizeof(int), stream);

    // Phase 1: Gx = X @ We_ih^T + be
    dim3 g1(TLEN / 128, G4H / 128);
    gx_gemm<<<g1, 256, 0, stream>>>(src_ids, emb_in, We_ih, be, wsf + OFF_GX);

    // Phase 2: encoder (cooperative for co-residency; flag barrier inside)
    {
        const float* a_Whh = We_hh;
        const float* a_Gx  = wsf + OFF_GX;
        float* a_ws  = wsf;
        int*   a_arr = (int*)(wsf + OFF_ARR);
        void* args[] = { &a_Whh, &a_Gx, &a_ws, &a_arr };
        hipLaunchCooperativeKernel(reinterpret_cast<void*>(enc_kernel),
                                   dim3(ENBLK), dim3(ENTHR), args, 0, stream);
    }

    // Phase 3: decoder — 6 ordinary kernels per step; boundaries = global sync
    for (int s = 0; s < NSTEP; ++s) {
        k_gates <<<NBLK, NTHR, 0, stream>>>(emb_tgt, Wd_ih, Wd_hh, bd, wsf, s);
        k_scores<<<NBLK, NTHR, 0, stream>>>(wsf, s);
        k_ctx   <<<NBLK, NTHR, 0, stream>>>(wsf);
        k_attn  <<<NBLK, NTHR, 0, stream>>>(W_attn, b_attn, wsf, s);
        k_logits<<<NBLK, NTHR, 0, stream>>>(W_out, b_out, wsf, outp, s);
        k_amax  <<<1,    NTHR, 0, stream>>>(wsf, outp, s);
    }
}

// Round 6
// 10296.258 us; speedup vs baseline: 7.6966x; 1.1117x over previous
//
#include <hip/hip_runtime.h>
#include <math.h>

#define HD     1024
#define TLEN   2048
#define G4H    4096
#define VOUTN  32000
#define NSTEP  50
#define BOS_ID 1
#define EOS_ID 2

// ---- decoder grids ----
#define NBLK 256
#define NTHR 256
#define JPB  (HD / NBLK)     // 4
#define TPB  (TLEN / NBLK)   // 8
#define RPB  (VOUTN / NBLK)  // 125

// ---- encoder grid ----
#define ENBLK 64
#define ENTHR 1024
#define EJPB  (HD / ENBLK)   // 16

#define SENTINEL 0xFFFFFFFFu   // -NaN bit pattern; h=o*tanh(c) can never be this

// ---- workspace layout (float offsets) ----
#define OFF_GX   ((size_t)0)                          // [TLEN][4H]
#define OFF_HS   (OFF_GX + (size_t)TLEN * G4H)        // [TLEN+1][HD]
#define OFF_HD   (OFF_HS + (size_t)(TLEN + 1) * HD)   // [2][HD] decoder h dbuf
#define OFF_SC   (OFF_HD + 2 * HD)                    // [TLEN] scores
#define OFF_DC   (OFF_SC + TLEN)                      // [HD] context
#define OFF_HTN  (OFF_DC + HD)                        // [HD] ht_new
#define OFF_BMV  (OFF_HTN + HD)                       // [NBLK] block argmax val
#define OFF_BMI  (OFF_BMV + NBLK)                     // [NBLK] block argmax idx (int)
#define OFF_CT   (OFF_BMI + NBLK)                     // [HD] decoder cell state
#define OFF_ST   (OFF_CT + HD)                        // [NSTEP+1] packed state (int)

#define DEV_SCOPE __HIP_MEMORY_SCOPE_AGENT

__device__ __forceinline__ float dload(const float* p) {
    return __hip_atomic_load(p, __ATOMIC_RELAXED, DEV_SCOPE);
}
__device__ __forceinline__ void dstore(float* p, float v) {
    __hip_atomic_store(p, v, __ATOMIC_RELAXED, DEV_SCOPE);
}

// ============================================================
// Kernel 0: sentinel-fill hs rows 1..TLEN (re-run every launch -> replay-safe)
// 2048 blocks x 256 threads x uint4 = exactly TLEN*HD floats
// ============================================================
__global__ __launch_bounds__(256) void fill_sentinel(float* __restrict__ hsrow1)
{
    const size_t i = ((size_t)blockIdx.x * 256 + threadIdx.x) * 4;
    uint4 v = make_uint4(SENTINEL, SENTINEL, SENTINEL, SENTINEL);
    *(uint4*)(hsrow1 + i) = v;
}

// ============================================================
// Kernel 1: Gx[t][r] = be[r] + sum_k emb[src_ids[t]][k] * We_ih[r][k]
// (unchanged — passed R1/R2/R5)
// ============================================================
__global__ __launch_bounds__(256) void gx_gemm(
    const int* __restrict__ src_ids,
    const float* __restrict__ emb,
    const float* __restrict__ Wih,
    const float* __restrict__ be,
    float* __restrict__ Gx)
{
    __shared__ float As[128][17];
    __shared__ float Bs[128][17];
    __shared__ int   sid[128];

    const int tid = threadIdx.x;
    const int t0 = blockIdx.x * 128;
    const int r0 = blockIdx.y * 128;

    if (tid < 128) sid[tid] = src_ids[t0 + tid];
    __syncthreads();

    const int tx = tid & 15;
    const int ty = tid >> 4;
    const int lrow = tid >> 1;
    const int lk   = (tid & 1) * 8;

    float acc[8][8];
#pragma unroll
    for (int i = 0; i < 8; ++i)
#pragma unroll
        for (int j = 0; j < 8; ++j) acc[i][j] = 0.f;

    for (int k0 = 0; k0 < HD; k0 += 16) {
        {
            const float* xa = emb + (size_t)sid[lrow] * HD + k0 + lk;
            float4 v0 = *(const float4*)xa;
            float4 v1 = *(const float4*)(xa + 4);
            As[lrow][lk + 0] = v0.x; As[lrow][lk + 1] = v0.y;
            As[lrow][lk + 2] = v0.z; As[lrow][lk + 3] = v0.w;
            As[lrow][lk + 4] = v1.x; As[lrow][lk + 5] = v1.y;
            As[lrow][lk + 6] = v1.z; As[lrow][lk + 7] = v1.w;
            const float* wb = Wih + (size_t)(r0 + lrow) * HD + k0 + lk;
            float4 w0 = *(const float4*)wb;
            float4 w1 = *(const float4*)(wb + 4);
            Bs[lrow][lk + 0] = w0.x; Bs[lrow][lk + 1] = w0.y;
            Bs[lrow][lk + 2] = w0.z; Bs[lrow][lk + 3] = w0.w;
            Bs[lrow][lk + 4] = w1.x; Bs[lrow][lk + 5] = w1.y;
            Bs[lrow][lk + 6] = w1.z; Bs[lrow][lk + 7] = w1.w;
        }
        __syncthreads();
#pragma unroll
        for (int kk = 0; kk < 16; ++kk) {
            float a[8], bv[8];
#pragma unroll
            for (int i = 0; i < 8; ++i) a[i]  = As[ty * 8 + i][kk];
#pragma unroll
            for (int j = 0; j < 8; ++j) bv[j] = Bs[tx * 8 + j][kk];
#pragma unroll
            for (int i = 0; i < 8; ++i)
#pragma unroll
                for (int j = 0; j < 8; ++j)
                    acc[i][j] = fmaf(a[i], bv[j], acc[i][j]);
        }
        __syncthreads();
    }

    float bev[8];
#pragma unroll
    for (int j = 0; j < 8; ++j) bev[j] = be[r0 + tx * 8 + j];
#pragma unroll
    for (int i = 0; i < 8; ++i) {
        const int t = t0 + ty * 8 + i;
        float* dst = Gx + (size_t)t * G4H + r0 + tx * 8;
#pragma unroll
        for (int j = 0; j < 8; ++j) dst[j] = acc[i][j] + bev[j];
    }
}

// ============================================================
// Kernel 2: encoder recurrence — sentinel data-poll (data IS the flag).
// Each thread polls its own element of h_t; producers just store h.
// No arrive flags, no vmcnt drain on the critical path.
// ============================================================
__global__ __launch_bounds__(1024, 4) void enc_kernel(
    const float* __restrict__ Whh,
    const float* __restrict__ Gx,
    float* __restrict__ wsf)
{
    float* hs   = wsf + OFF_HS;
    float* hd   = wsf + OFF_HD;
    float* cdec = wsf + OFF_CT;
    int*   st   = (int*)(wsf + OFF_ST);

    const int b    = blockIdx.x;
    const int tid  = threadIdx.x;
    const int w    = tid >> 6;
    const int lane = tid & 63;
    const int j0   = b * EJPB;
    const int g    = w >> 2;
    const int e0   = (w & 3) * 4;

    __shared__ float bufH[HD];
    __shared__ float g_s[64];
    __shared__ float c_s[EJPB];

    float wreg[4][16];
#pragma unroll
    for (int d = 0; d < 4; ++d) {
        const int grow = g * HD + j0 + e0 + d;
        const float* src = Whh + (size_t)grow * HD + lane;
#pragma unroll
        for (int q = 0; q < 16; ++q) wreg[d][q] = src[q * 64];
    }

    if (tid < EJPB) c_s[tid] = 0.f;

    for (int t = 0; t < TLEN; ++t) {
        // data-poll: wait for this thread's element of h_t (row 0 = zeros, ready)
        {
            const float* src = hs + (size_t)t * HD + tid;
            float v = dload(src);
            while (__float_as_uint(v) == SENTINEL) {
                __builtin_amdgcn_s_sleep(1);
                v = dload(src);
            }
            bufH[tid] = v;
        }
        __syncthreads();

        float acc[4];
#pragma unroll
        for (int d = 0; d < 4; ++d) {
            float a = 0.f;
#pragma unroll
            for (int q = 0; q < 16; ++q)
                a = fmaf(wreg[d][q], bufH[q * 64 + lane], a);
#pragma unroll
            for (int off = 32; off > 0; off >>= 1) a += __shfl_down(a, off);
            acc[d] = a;
        }
        if (lane == 0) {
#pragma unroll
            for (int d = 0; d < 4; ++d) g_s[g * 16 + e0 + d] = acc[d];
        }
        __syncthreads();

        if (tid < EJPB) {
            const int j = j0 + tid;
            const float* gx = Gx + (size_t)t * G4H;
            const float gi = g_s[tid]      + gx[0 * HD + j];
            const float gf = g_s[16 + tid] + gx[1 * HD + j];
            const float gg = g_s[32 + tid] + gx[2 * HD + j];
            const float go = g_s[48 + tid] + gx[3 * HD + j];
            const float i_ = 1.f / (1.f + expf(-gi));
            const float f_ = 1.f / (1.f + expf(-gf));
            const float o_ = 1.f / (1.f + expf(-go));
            const float g2 = tanhf(gg);
            const float c2 = f_ * c_s[tid] + i_ * g2;
            c_s[tid] = c2;
            dstore(hs + (size_t)(t + 1) * HD + j, o_ * tanhf(c2));  // store IS the signal
        }
        // no drain, no flag — consumers poll the data itself
    }

    // seed decoder state (kernel boundary publishes)
    if (tid < EJPB) {
        cdec[j0 + tid] = c_s[tid];
        hd[j0 + tid]   = hs[(size_t)TLEN * HD + j0 + tid];
    }
    if (b == 0 && tid == 0) st[0] = BOS_ID;   // done=0, wid=BOS
}

// ============================================================
// Decoder step kernels — ordinary launches (proven R5); boundary = sync.
// st[s] = (done<<16) | wid  (state ENTERING step s).
// ============================================================

// K1: LSTM gates -> hnxt, cdec update
__global__ __launch_bounds__(256) void k_gates(
    const float* __restrict__ embT,
    const float* __restrict__ Wdih,
    const float* __restrict__ Wdhh,
    const float* __restrict__ bdv,
    float* __restrict__ wsf, int s)
{
    float* hd   = wsf + OFF_HD;
    float* cdec = wsf + OFF_CT;
    const int* st = (const int*)(wsf + OFF_ST);

    const int b    = blockIdx.x;
    const int tid  = threadIdx.x;
    const int w    = tid >> 6;
    const int lane = tid & 63;
    const int j0   = b * JPB;

    const float* hcur = hd + (s & 1) * HD;
    float*       hnxt = hd + ((s + 1) & 1) * HD;

    __shared__ float bufAB[2 * HD];
    __shared__ float g_s[4 * JPB];
    const float4* buf4 = (const float4*)bufAB;

    const int widv = st[s] & 0xFFFF;
    const float* x = embT + (size_t)widv * HD;
    for (int i = tid; i < HD; i += NTHR) {
        bufAB[i]      = x[i];
        bufAB[HD + i] = hcur[i];
    }
    __syncthreads();

#pragma unroll
    for (int d = 0; d < 4; ++d) {
        const int grow = w * HD + j0 + d;
        const float4* wi4 = (const float4*)(Wdih + (size_t)grow * HD);
        const float4* wh4 = (const float4*)(Wdhh + (size_t)grow * HD);
        float4 a4 = make_float4(0.f, 0.f, 0.f, 0.f);
#pragma unroll
        for (int q = 0; q < 4; ++q) {
            float4 wv = wi4[q * 64 + lane], xv = buf4[q * 64 + lane];
            a4.x = fmaf(wv.x, xv.x, a4.x); a4.y = fmaf(wv.y, xv.y, a4.y);
            a4.z = fmaf(wv.z, xv.z, a4.z); a4.w = fmaf(wv.w, xv.w, a4.w);
            float4 wv2 = wh4[q * 64 + lane], hv = buf4[256 + q * 64 + lane];
            a4.x = fmaf(wv2.x, hv.x, a4.x); a4.y = fmaf(wv2.y, hv.y, a4.y);
            a4.z = fmaf(wv2.z, hv.z, a4.z); a4.w = fmaf(wv2.w, hv.w, a4.w);
        }
        float a = (a4.x + a4.y) + (a4.z + a4.w);
#pragma unroll
        for (int off = 32; off > 0; off >>= 1) a += __shfl_down(a, off);
        if (lane == 0) g_s[w * 4 + d] = a;
    }
    __syncthreads();

    if (tid < JPB) {
        const int j = j0 + tid;
        const float gi = g_s[0 * 4 + tid] + bdv[0 * HD + j];
        const float gf = g_s[1 * 4 + tid] + bdv[1 * HD + j];
        const float gg = g_s[2 * 4 + tid] + bdv[2 * HD + j];
        const float go = g_s[3 * 4 + tid] + bdv[3 * HD + j];
        const float i_ = 1.f / (1.f + expf(-gi));
        const float f_ = 1.f / (1.f + expf(-gf));
        const float o_ = 1.f / (1.f + expf(-go));
        const float g2 = tanhf(gg);
        const float c2 = f_ * cdec[j] + i_ * g2;
        cdec[j] = c2;
        hnxt[j] = o_ * tanhf(c2);
    }
}

// K2: attention scores sc[t] = hs[t+1] . hnxt
__global__ __launch_bounds__(256) void k_scores(float* __restrict__ wsf, int s)
{
    const float* hs = wsf + OFF_HS;
    const float* hnxt = wsf + OFF_HD + (size_t)((s + 1) & 1) * HD;
    float* sc = wsf + OFF_SC;

    const int b    = blockIdx.x;
    const int tid  = threadIdx.x;
    const int w    = tid >> 6;
    const int lane = tid & 63;

    __shared__ float bufH[HD];
    const float4* buf4 = (const float4*)bufH;
    for (int i = tid; i < HD; i += NTHR) bufH[i] = hnxt[i];
    __syncthreads();

#pragma unroll
    for (int d = 0; d < 2; ++d) {
        const int t = b * TPB + w * 2 + d;
        const float4* hr4 = (const float4*)(hs + (size_t)(t + 1) * HD);
        float4 a4 = make_float4(0.f, 0.f, 0.f, 0.f);
#pragma unroll
        for (int q = 0; q < 4; ++q) {
            float4 hv = hr4[q * 64 + lane], bv = buf4[q * 64 + lane];
            a4.x = fmaf(hv.x, bv.x, a4.x); a4.y = fmaf(hv.y, bv.y, a4.y);
            a4.z = fmaf(hv.z, bv.z, a4.z); a4.w = fmaf(hv.w, bv.w, a4.w);
        }
        float a = (a4.x + a4.y) + (a4.z + a4.w);
#pragma unroll
        for (int off = 32; off > 0; off >>= 1) a += __shfl_down(a, off);
        if (lane == 0) sc[t] = a;
    }
}

// K3: block-redundant softmax over sc + context slice dctx[j0..j0+3]
__global__ __launch_bounds__(256) void k_ctx(float* __restrict__ wsf)
{
    const float* hs = wsf + OFF_HS;
    const float* sc = wsf + OFF_SC;
    float* dctx = wsf + OFF_DC;

    const int b    = blockIdx.x;
    const int tid  = threadIdx.x;
    const int w    = tid >> 6;
    const int lane = tid & 63;
    const int j0   = b * JPB;

    __shared__ float sc_s[TLEN];
    __shared__ float red[NTHR];

    for (int t = tid; t < TLEN; t += NTHR) sc_s[t] = sc[t];
    __syncthreads();

    float lm = -INFINITY;
    for (int t = tid; t < TLEN; t += NTHR) lm = fmaxf(lm, sc_s[t]);
    red[tid] = lm; __syncthreads();
    for (int s2 = NTHR / 2; s2 > 0; s2 >>= 1) {
        if (tid < s2) red[tid] = fmaxf(red[tid], red[tid + s2]);
        __syncthreads();
    }
    const float m = red[0]; __syncthreads();
    float lz = 0.f;
    for (int t = tid; t < TLEN; t += NTHR) lz += expf(sc_s[t] - m);
    red[tid] = lz; __syncthreads();
    for (int s2 = NTHR / 2; s2 > 0; s2 >>= 1) {
        if (tid < s2) red[tid] += red[tid + s2];
        __syncthreads();
    }
    const float Zi = 1.f / red[0]; __syncthreads();

    const int j = j0 + w;
    float a = 0.f;
#pragma unroll
    for (int it = 0; it < TLEN / 64; ++it) {
        const int t = lane + it * 64;
        const float wt = expf(sc_s[t] - m) * Zi;
        a = fmaf(wt, hs[(size_t)(t + 1) * HD + j], a);
    }
#pragma unroll
    for (int off = 32; off > 0; off >>= 1) a += __shfl_down(a, off);
    if (lane == 0) dctx[j] = a;
}

// K4: ht_new = tanh(W_attn @ [d; ht] + b_attn)
__global__ __launch_bounds__(256) void k_attn(
    const float* __restrict__ Wattn,
    const float* __restrict__ battn,
    float* __restrict__ wsf, int s)
{
    const float* dctx = wsf + OFF_DC;
    const float* hnxt = wsf + OFF_HD + (size_t)((s + 1) & 1) * HD;
    float* htn = wsf + OFF_HTN;

    const int b    = blockIdx.x;
    const int tid  = threadIdx.x;
    const int w    = tid >> 6;
    const int lane = tid & 63;
    const int j0   = b * JPB;

    __shared__ float bufAB[2 * HD];
    const float4* buf4 = (const float4*)bufAB;
    for (int i = tid; i < HD; i += NTHR) {
        bufAB[i]      = dctx[i];
        bufAB[HD + i] = hnxt[i];
    }
    __syncthreads();

    const int j = j0 + w;
    const float4* wr4 = (const float4*)(Wattn + (size_t)j * (2 * HD));
    float4 a4 = make_float4(0.f, 0.f, 0.f, 0.f);
#pragma unroll
    for (int q = 0; q < 8; ++q) {
        float4 wv = wr4[q * 64 + lane], bv = buf4[q * 64 + lane];
        a4.x = fmaf(wv.x, bv.x, a4.x); a4.y = fmaf(wv.y, bv.y, a4.y);
        a4.z = fmaf(wv.z, bv.z, a4.z); a4.w = fmaf(wv.w, bv.w, a4.w);
    }
    float a = (a4.x + a4.y) + (a4.z + a4.w);
#pragma unroll
    for (int off = 32; off > 0; off >>= 1) a += __shfl_down(a, off);
    if (lane == 0) htn[j] = tanhf(a + battn[j]);
}

// K5: logits = W_out @ ht_new + b_out ; masked write ; per-block argmax
__global__ __launch_bounds__(256) void k_logits(
    const float* __restrict__ Wout,
    const float* __restrict__ bout,
    float* __restrict__ wsf,
    float* __restrict__ out, int s)
{
    const float* htn = wsf + OFF_HTN;
    float* bmv = wsf + OFF_BMV;
    int*   bmi = (int*)(wsf + OFF_BMI);
    const int* st = (const int*)(wsf + OFF_ST);

    const int b    = blockIdx.x;
    const int tid  = threadIdx.x;
    const int w    = tid >> 6;
    const int lane = tid & 63;

    __shared__ float bufH[HD];
    __shared__ float red[4];
    __shared__ int   redi[4];
    const float4* buf4 = (const float4*)bufH;

    const int donev = (st[s] >> 16) & 1;
    for (int i = tid; i < HD; i += NTHR) bufH[i] = htn[i];
    __syncthreads();

    const int r0b = b * RPB;
    const int rbeg = r0b + w * 32;
    const int rend = min(r0b + RPB, rbeg + 32);
    float bv = -INFINITY; int bi = 0x7fffffff;
    for (int r = rbeg; r < rend; r += 2) {
        const int two = (r + 1 < rend);
        const float4* w0 = (const float4*)(Wout + (size_t)r * HD);
        const float4* w1 = (const float4*)(Wout + (size_t)(r + two) * HD);
        float4 a04 = make_float4(0.f, 0.f, 0.f, 0.f);
        float4 a14 = make_float4(0.f, 0.f, 0.f, 0.f);
#pragma unroll
        for (int q = 0; q < 4; ++q) {
            float4 hv = buf4[q * 64 + lane];
            float4 x0 = w0[q * 64 + lane];
            float4 x1 = w1[q * 64 + lane];
            a04.x = fmaf(x0.x, hv.x, a04.x); a04.y = fmaf(x0.y, hv.y, a04.y);
            a04.z = fmaf(x0.z, hv.z, a04.z); a04.w = fmaf(x0.w, hv.w, a04.w);
            a14.x = fmaf(x1.x, hv.x, a14.x); a14.y = fmaf(x1.y, hv.y, a14.y);
            a14.z = fmaf(x1.z, hv.z, a14.z); a14.w = fmaf(x1.w, hv.w, a14.w);
        }
        float a0 = (a04.x + a04.y) + (a04.z + a04.w);
        float a1 = (a14.x + a14.y) + (a14.z + a14.w);
#pragma unroll
        for (int off = 32; off > 0; off >>= 1) {
            a0 += __shfl_down(a0, off);
            a1 += __shfl_down(a1, off);
        }
        if (lane == 0) {
            a0 += bout[r];
            out[NSTEP + (size_t)s * VOUTN + r] = donev ? 0.f : a0;
            if (a0 > bv) { bv = a0; bi = r; }
            if (two) {
                a1 += bout[r + 1];
                out[NSTEP + (size_t)s * VOUTN + r + 1] = donev ? 0.f : a1;
                if (a1 > bv) { bv = a1; bi = r + 1; }
            }
        }
    }
    if (lane == 0) { red[w] = bv; redi[w] = bi; }
    __syncthreads();
    if (tid == 0) {
        float v = red[0]; int ii = redi[0];
#pragma unroll
        for (int q = 1; q < 4; ++q)
            if (red[q] > v || (red[q] == v && redi[q] < ii)) { v = red[q]; ii = redi[q]; }
        bmv[b] = v; bmi[b] = ii;
    }
}

// K6: global argmax (first index on ties), token + next state
__global__ __launch_bounds__(256) void k_amax(
    float* __restrict__ wsf, float* __restrict__ out, int s)
{
    const float* bmv = wsf + OFF_BMV;
    const int*   bmi = (const int*)(wsf + OFF_BMI);
    int* st = (int*)(wsf + OFF_ST);

    const int tid = threadIdx.x;
    __shared__ float red[NTHR];
    __shared__ int   redi[NTHR];

    red[tid] = bmv[tid]; redi[tid] = bmi[tid];
    __syncthreads();
    for (int s2 = NTHR / 2; s2 > 0; s2 >>= 1) {
        if (tid < s2) {
            if (red[tid + s2] > red[tid] ||
                (red[tid + s2] == red[tid] && redi[tid + s2] < redi[tid])) {
                red[tid] = red[tid + s2]; redi[tid] = redi[tid + s2];
            }
        }
        __syncthreads();
    }
    if (tid == 0) {
        const int nid = redi[0];
        const int donev = (st[s] >> 16) & 1;
        out[s] = donev ? 0.f : (float)nid;
        const int done2 = donev | (nid == EOS_ID);
        st[s + 1] = (done2 << 16) | nid;
    }
}

extern "C" void kernel_launch(void* const* d_in, const int* in_sizes, int n_in,
                              void* d_out, int out_size, void* d_ws, size_t ws_size,
                              hipStream_t stream) {
    (void)in_sizes; (void)n_in; (void)out_size; (void)ws_size;
    const int*   src_ids = (const int*)  d_in[0];
    const float* emb_in  = (const float*)d_in[1];
    const float* We_ih   = (const float*)d_in[2];
    const float* We_hh   = (const float*)d_in[3];
    const float* be      = (const float*)d_in[4];
    const float* emb_tgt = (const float*)d_in[5];
    const float* Wd_ih   = (const float*)d_in[6];
    const float* Wd_hh   = (const float*)d_in[7];
    const float* bd      = (const float*)d_in[8];
    const float* W_attn  = (const float*)d_in[9];
    const float* b_attn  = (const float*)d_in[10];
    const float* W_out   = (const float*)d_in[11];
    const float* b_out   = (const float*)d_in[12];

    float* outp = (float*)d_out;
    float* wsf  = (float*)d_ws;

    // deterministic init every call: h0 row zeros + sentinel rows 1..TLEN
    hipMemsetAsync(wsf + OFF_HS, 0, HD * sizeof(float), stream);
    fill_sentinel<<<TLEN, 256, 0, stream>>>(wsf + OFF_HS + HD);

    // Phase 1: Gx = X @ We_ih^T + be
    dim3 g1(TLEN / 128, G4H / 128);
    gx_gemm<<<g1, 256, 0, stream>>>(src_ids, emb_in, We_ih, be, wsf + OFF_GX);

    // Phase 2: encoder (cooperative for co-residency; sentinel data-poll inside)
    {
        const float* a_Whh = We_hh;
        const float* a_Gx  = wsf + OFF_GX;
        float* a_ws  = wsf;
        void* args[] = { &a_Whh, &a_Gx, &a_ws };
        hipLaunchCooperativeKernel(reinterpret_cast<void*>(enc_kernel),
                                   dim3(ENBLK), dim3(ENTHR), args, 0, stream);
    }

    // Phase 3: decoder — 6 ordinary kernels per step; boundaries = global sync
    for (int s = 0; s < NSTEP; ++s) {
        k_gates <<<NBLK, NTHR, 0, stream>>>(emb_tgt, Wd_ih, Wd_hh, bd, wsf, s);
        k_scores<<<NBLK, NTHR, 0, stream>>>(wsf, s);
        k_ctx   <<<NBLK, NTHR, 0, stream>>>(wsf);
        k_attn  <<<NBLK, NTHR, 0, stream>>>(W_attn, b_attn, wsf, s);
        k_logits<<<NBLK, NTHR, 0, stream>>>(W_out, b_out, wsf, outp, s);
        k_amax  <<<1,    NTHR, 0, stream>>>(wsf, outp, s);
    }
}

// Round 7
// 8521.647 us; speedup vs baseline: 9.2995x; 1.2082x over previous
//
#include <hip/hip_runtime.h>
#include <hip/hip_cooperative_groups.h>
#include <math.h>

#define HD     1024
#define TLEN   2048
#define G4H    4096
#define VOUTN  32000
#define NSTEP  50
#define BOS_ID 1
#define EOS_ID 2

// ---- decoder grids ----
#define NBLK   256
#define NTHR   256
#define JPB    (HD / NBLK)     // 4
#define TPB    (TLEN / NBLK)   // 8
#define NBLK_L 500             // k_logits blocks (2/CU); 500*64 = 32000
#define RPW_L  16              // rows per wave in k_logits

// ---- encoder grid ----
#define ENBLK 64
#define ENTHR 1024
#define EJPB  (HD / ENBLK)   // 16

#define SENTINEL 0xFFFFFFFFu   // -NaN; h=o*tanh(c) can never be this

// ---- workspace layout (float offsets) ----
#define OFF_GX   ((size_t)0)                          // [TLEN][4H]
#define OFF_HS   (OFF_GX + (size_t)TLEN * G4H)        // [TLEN+1][HD]
#define OFF_HD   (OFF_HS + (size_t)(TLEN + 1) * HD)   // [2][HD] decoder h dbuf
#define OFF_SC   (OFF_HD + 2 * HD)                    // [TLEN] scores
#define OFF_DC   (OFF_SC + TLEN)                      // [HD] context
#define OFF_HTN  (OFF_DC + HD)                        // [HD] ht_new
#define OFF_BMV  (OFF_HTN + HD)                       // [512] block argmax val (500 used)
#define OFF_BMI  (OFF_BMV + 512)                      // [512] block argmax idx (int)
#define OFF_CT   (OFF_BMI + 512)                      // [HD] decoder cell state
#define OFF_ST   (OFF_CT + HD)                        // [NSTEP+1] packed state (int) +pad
#define OFF_HST  (OFF_ST + 64)                        // [HD][TLEN] hs transpose (optional)
#define WS_NEED_HST ((OFF_HST + (size_t)HD * TLEN) * sizeof(float))

#define DEV_SCOPE __HIP_MEMORY_SCOPE_AGENT

__device__ __forceinline__ float dload(const float* p) {
    return __hip_atomic_load(p, __ATOMIC_RELAXED, DEV_SCOPE);
}
__device__ __forceinline__ void dstore(float* p, float v) {
    __hip_atomic_store(p, v, __ATOMIC_RELAXED, DEV_SCOPE);
}

// ============================================================
// Kernel 0: sentinel-fill hs rows 1..TLEN (replay-safe)
// ============================================================
__global__ __launch_bounds__(256) void fill_sentinel(float* __restrict__ hsrow1)
{
    const size_t i = ((size_t)blockIdx.x * 256 + threadIdx.x) * 4;
    uint4 v = make_uint4(SENTINEL, SENTINEL, SENTINEL, SENTINEL);
    *(uint4*)(hsrow1 + i) = v;
}

// ============================================================
// Kernel 1: Gx = X @ We_ih^T + be  (unchanged — proven)
// ============================================================
__global__ __launch_bounds__(256) void gx_gemm(
    const int* __restrict__ src_ids,
    const float* __restrict__ emb,
    const float* __restrict__ Wih,
    const float* __restrict__ be,
    float* __restrict__ Gx)
{
    __shared__ float As[128][17];
    __shared__ float Bs[128][17];
    __shared__ int   sid[128];

    const int tid = threadIdx.x;
    const int t0 = blockIdx.x * 128;
    const int r0 = blockIdx.y * 128;

    if (tid < 128) sid[tid] = src_ids[t0 + tid];
    __syncthreads();

    const int tx = tid & 15;
    const int ty = tid >> 4;
    const int lrow = tid >> 1;
    const int lk   = (tid & 1) * 8;

    float acc[8][8];
#pragma unroll
    for (int i = 0; i < 8; ++i)
#pragma unroll
        for (int j = 0; j < 8; ++j) acc[i][j] = 0.f;

    for (int k0 = 0; k0 < HD; k0 += 16) {
        {
            const float* xa = emb + (size_t)sid[lrow] * HD + k0 + lk;
            float4 v0 = *(const float4*)xa;
            float4 v1 = *(const float4*)(xa + 4);
            As[lrow][lk + 0] = v0.x; As[lrow][lk + 1] = v0.y;
            As[lrow][lk + 2] = v0.z; As[lrow][lk + 3] = v0.w;
            As[lrow][lk + 4] = v1.x; As[lrow][lk + 5] = v1.y;
            As[lrow][lk + 6] = v1.z; As[lrow][lk + 7] = v1.w;
            const float* wb = Wih + (size_t)(r0 + lrow) * HD + k0 + lk;
            float4 w0 = *(const float4*)wb;
            float4 w1 = *(const float4*)(wb + 4);
            Bs[lrow][lk + 0] = w0.x; Bs[lrow][lk + 1] = w0.y;
            Bs[lrow][lk + 2] = w0.z; Bs[lrow][lk + 3] = w0.w;
            Bs[lrow][lk + 4] = w1.x; Bs[lrow][lk + 5] = w1.y;
            Bs[lrow][lk + 6] = w1.z; Bs[lrow][lk + 7] = w1.w;
        }
        __syncthreads();
#pragma unroll
        for (int kk = 0; kk < 16; ++kk) {
            float a[8], bv[8];
#pragma unroll
            for (int i = 0; i < 8; ++i) a[i]  = As[ty * 8 + i][kk];
#pragma unroll
            for (int j = 0; j < 8; ++j) bv[j] = Bs[tx * 8 + j][kk];
#pragma unroll
            for (int i = 0; i < 8; ++i)
#pragma unroll
                for (int j = 0; j < 8; ++j)
                    acc[i][j] = fmaf(a[i], bv[j], acc[i][j]);
        }
        __syncthreads();
    }

    float bev[8];
#pragma unroll
    for (int j = 0; j < 8; ++j) bev[j] = be[r0 + tx * 8 + j];
#pragma unroll
    for (int i = 0; i < 8; ++i) {
        const int t = t0 + ty * 8 + i;
        float* dst = Gx + (size_t)t * G4H + r0 + tx * 8;
#pragma unroll
        for (int j = 0; j < 8; ++j) dst[j] = acc[i][j] + bev[j];
    }
}

// ============================================================
// Kernel 2: encoder — sentinel data-poll (proven R6) + Gx LDS prefetch.
// ============================================================
__global__ __launch_bounds__(1024, 4) void enc_kernel(
    const float* __restrict__ Whh,
    const float* __restrict__ Gx,
    float* __restrict__ wsf)
{
    float* hs   = wsf + OFF_HS;
    float* hd   = wsf + OFF_HD;
    float* cdec = wsf + OFF_CT;
    int*   st   = (int*)(wsf + OFF_ST);

    const int b    = blockIdx.x;
    const int tid  = threadIdx.x;
    const int w    = tid >> 6;
    const int lane = tid & 63;
    const int j0   = b * EJPB;
    const int g    = w >> 2;
    const int e0   = (w & 3) * 4;

    __shared__ float bufH[HD];
    __shared__ float g_s[64];
    __shared__ float c_s[EJPB];
    __shared__ float gxbuf[64];   // Gx row slice [gate][elem], prefetched

    float wreg[4][16];
#pragma unroll
    for (int d = 0; d < 4; ++d) {
        const int grow = g * HD + j0 + e0 + d;
        const float* src = Whh + (size_t)grow * HD + lane;
#pragma unroll
        for (int q = 0; q < 16; ++q) wreg[d][q] = src[q * 64];
    }

    if (tid < EJPB) c_s[tid] = 0.f;

    for (int t = 0; t < TLEN; ++t) {
        // data-poll: this thread's element of h_t (row 0 = zeros, ready)
        {
            const float* src = hs + (size_t)t * HD + tid;
            float v = dload(src);
            while (__float_as_uint(v) == SENTINEL) {
                __builtin_amdgcn_s_sleep(1);
                v = dload(src);
            }
            bufH[tid] = v;
        }
        __syncthreads();

        // prefetch this block's Gx slice for step t (overlaps matvec)
        if (tid >= 64 && tid < 128) {
            const int idx = tid - 64;          // 0..63
            const int gg2 = idx >> 4;          // gate
            const int ee  = idx & 15;          // elem
            gxbuf[idx] = Gx[(size_t)t * G4H + gg2 * HD + j0 + ee];
        }

        float acc[4];
#pragma unroll
        for (int d = 0; d < 4; ++d) {
            float a = 0.f;
#pragma unroll
            for (int q = 0; q < 16; ++q)
                a = fmaf(wreg[d][q], bufH[q * 64 + lane], a);
#pragma unroll
            for (int off = 32; off > 0; off >>= 1) a += __shfl_down(a, off);
            acc[d] = a;
        }
        if (lane == 0) {
#pragma unroll
            for (int d = 0; d < 4; ++d) g_s[g * 16 + e0 + d] = acc[d];
        }
        __syncthreads();

        if (tid < EJPB) {
            const int j = j0 + tid;
            const float gi = g_s[tid]      + gxbuf[tid];
            const float gf = g_s[16 + tid] + gxbuf[16 + tid];
            const float gg = g_s[32 + tid] + gxbuf[32 + tid];
            const float go = g_s[48 + tid] + gxbuf[48 + tid];
            const float i_ = 1.f / (1.f + expf(-gi));
            const float f_ = 1.f / (1.f + expf(-gf));
            const float o_ = 1.f / (1.f + expf(-go));
            const float g2 = tanhf(gg);
            const float c2 = f_ * c_s[tid] + i_ * g2;
            c_s[tid] = c2;
            dstore(hs + (size_t)(t + 1) * HD + j, o_ * tanhf(c2));  // store IS the signal
        }
    }

    // seed decoder state (kernel boundary publishes)
    if (tid < EJPB) {
        cdec[j0 + tid] = c_s[tid];
        hd[j0 + tid]   = hs[(size_t)TLEN * HD + j0 + tid];
    }
    if (b == 0 && tid == 0) st[0] = BOS_ID;   // done=0, wid=BOS
}

// ============================================================
// Kernel 2b: tiled transpose hsT[j][t] = hs[t+1][j]  (coalesced k_ctx)
// grid (TLEN/32, HD/32), 256 threads
// ============================================================
__global__ __launch_bounds__(256) void k_transpose(
    const float* __restrict__ hs, float* __restrict__ hsT)
{
    __shared__ float tile[32][33];
    const int t0  = blockIdx.x * 32;
    const int j0b = blockIdx.y * 32;
    const int tx  = threadIdx.x & 31;
    const int ty  = threadIdx.x >> 5;   // 0..7
#pragma unroll
    for (int k = 0; k < 4; ++k) {
        const int trow = t0 + ty + k * 8;
        tile[ty + k * 8][tx] = hs[(size_t)(trow + 1) * HD + j0b + tx];
    }
    __syncthreads();
#pragma unroll
    for (int k = 0; k < 4; ++k) {
        const int j = j0b + ty + k * 8;
        hsT[(size_t)j * TLEN + t0 + tx] = tile[tx][ty + k * 8];
    }
}

// ============================================================
// K1: gates — folds previous step's global argmax (from bmv/bmi),
// maintains st[] chain (block 0), then LSTM gates -> hnxt, cdec.
// ============================================================
__global__ __launch_bounds__(256) void k_gates(
    const float* __restrict__ embT,
    const float* __restrict__ Wdih,
    const float* __restrict__ Wdhh,
    const float* __restrict__ bdv,
    float* __restrict__ wsf,
    float* __restrict__ out, int s)
{
    float* hd   = wsf + OFF_HD;
    float* cdec = wsf + OFF_CT;
    int*   st   = (int*)(wsf + OFF_ST);
    const float* bmv = wsf + OFF_BMV;
    const int*   bmi = (const int*)(wsf + OFF_BMI);

    const int b    = blockIdx.x;
    const int tid  = threadIdx.x;
    const int w    = tid >> 6;
    const int lane = tid & 63;
    const int j0   = b * JPB;

    const float* hcur = hd + (s & 1) * HD;
    float*       hnxt = hd + ((s + 1) & 1) * HD;

    __shared__ float bufAB[2 * HD];
    __shared__ float g_s[4 * JPB];
    __shared__ float rv[NTHR];
    __shared__ int   ri[NTHR];
    __shared__ int   s_wid;

    // stage hcur (independent of token)
    for (int i = tid; i < HD; i += NTHR) bufAB[HD + i] = hcur[i];

    if (s == 0) {
        if (tid == 0) s_wid = st[0] & 0xFFFF;
        __syncthreads();
    } else {
        // redundant global argmax over the 500 block candidates of step s-1
        float v1 = bmv[tid]; int i1 = bmi[tid];
        if (tid + 256 < NBLK_L) {
            float v2 = bmv[tid + 256]; int i2 = bmi[tid + 256];
            if (v2 > v1 || (v2 == v1 && i2 < i1)) { v1 = v2; i1 = i2; }
        }
        rv[tid] = v1; ri[tid] = i1;
        __syncthreads();
        for (int s2 = 128; s2 > 0; s2 >>= 1) {
            if (tid < s2) {
                if (rv[tid + s2] > rv[tid] ||
                    (rv[tid + s2] == rv[tid] && ri[tid + s2] < ri[tid])) {
                    rv[tid] = rv[tid + s2]; ri[tid] = ri[tid + s2];
                }
            }
            __syncthreads();
        }
        if (tid == 0) {
            const int nid   = ri[0];
            const int prev  = st[s - 1];
            const int dprev = (prev >> 16) & 1;
            const int dnew  = dprev | (nid == EOS_ID);
            s_wid = nid;
            if (b == 0) {
                out[s - 1] = dprev ? 0.f : (float)nid;   // token masked w/ PRE-update done
                st[s] = (dnew << 16) | nid;
            }
        }
        __syncthreads();
    }

    const float* x = embT + (size_t)s_wid * HD;
    for (int i = tid; i < HD; i += NTHR) bufAB[i] = x[i];
    __syncthreads();

    const float4* buf4 = (const float4*)bufAB;
#pragma unroll
    for (int d = 0; d < 4; ++d) {
        const int grow = w * HD + j0 + d;
        const float4* wi4 = (const float4*)(Wdih + (size_t)grow * HD);
        const float4* wh4 = (const float4*)(Wdhh + (size_t)grow * HD);
        float4 a4 = make_float4(0.f, 0.f, 0.f, 0.f);
#pragma unroll
        for (int q = 0; q < 4; ++q) {
            float4 wv = wi4[q * 64 + lane], xv = buf4[q * 64 + lane];
            a4.x = fmaf(wv.x, xv.x, a4.x); a4.y = fmaf(wv.y, xv.y, a4.y);
            a4.z = fmaf(wv.z, xv.z, a4.z); a4.w = fmaf(wv.w, xv.w, a4.w);
            float4 wv2 = wh4[q * 64 + lane], hv = buf4[256 + q * 64 + lane];
            a4.x = fmaf(wv2.x, hv.x, a4.x); a4.y = fmaf(wv2.y, hv.y, a4.y);
            a4.z = fmaf(wv2.z, hv.z, a4.z); a4.w = fmaf(wv2.w, hv.w, a4.w);
        }
        float a = (a4.x + a4.y) + (a4.z + a4.w);
#pragma unroll
        for (int off = 32; off > 0; off >>= 1) a += __shfl_down(a, off);
        if (lane == 0) g_s[w * 4 + d] = a;
    }
    __syncthreads();

    if (tid < JPB) {
        const int j = j0 + tid;
        const float gi = g_s[0 * 4 + tid] + bdv[0 * HD + j];
        const float gf = g_s[1 * 4 + tid] + bdv[1 * HD + j];
        const float gg = g_s[2 * 4 + tid] + bdv[2 * HD + j];
        const float go = g_s[3 * 4 + tid] + bdv[3 * HD + j];
        const float i_ = 1.f / (1.f + expf(-gi));
        const float f_ = 1.f / (1.f + expf(-gf));
        const float o_ = 1.f / (1.f + expf(-go));
        const float g2 = tanhf(gg);
        const float c2 = f_ * cdec[j] + i_ * g2;
        cdec[j] = c2;
        hnxt[j] = o_ * tanhf(c2);
    }
}

// K2: attention scores sc[t] = hs[t+1] . hnxt  (unchanged)
__global__ __launch_bounds__(256) void k_scores(float* __restrict__ wsf, int s)
{
    const float* hs = wsf + OFF_HS;
    const float* hnxt = wsf + OFF_HD + (size_t)((s + 1) & 1) * HD;
    float* sc = wsf + OFF_SC;

    const int b    = blockIdx.x;
    const int tid  = threadIdx.x;
    const int w    = tid >> 6;
    const int lane = tid & 63;

    __shared__ float bufH[HD];
    const float4* buf4 = (const float4*)bufH;
    for (int i = tid; i < HD; i += NTHR) bufH[i] = hnxt[i];
    __syncthreads();

#pragma unroll
    for (int d = 0; d < 2; ++d) {
        const int t = b * TPB + w * 2 + d;
        const float4* hr4 = (const float4*)(hs + (size_t)(t + 1) * HD);
        float4 a4 = make_float4(0.f, 0.f, 0.f, 0.f);
#pragma unroll
        for (int q = 0; q < 4; ++q) {
            float4 hv = hr4[q * 64 + lane], bv = buf4[q * 64 + lane];
            a4.x = fmaf(hv.x, bv.x, a4.x); a4.y = fmaf(hv.y, bv.y, a4.y);
            a4.z = fmaf(hv.z, bv.z, a4.z); a4.w = fmaf(hv.w, bv.w, a4.w);
        }
        float a = (a4.x + a4.y) + (a4.z + a4.w);
#pragma unroll
        for (int off = 32; off > 0; off >>= 1) a += __shfl_down(a, off);
        if (lane == 0) sc[t] = a;
    }
}

// K3: block-redundant softmax + context slice; coalesced via hsT when available
__global__ __launch_bounds__(256) void k_ctx(
    float* __restrict__ wsf, const float* __restrict__ hsT)
{
    const float* hs = wsf + OFF_HS;
    const float* sc = wsf + OFF_SC;
    float* dctx = wsf + OFF_DC;

    const int b    = blockIdx.x;
    const int tid  = threadIdx.x;
    const int w    = tid >> 6;
    const int lane = tid & 63;
    const int j0   = b * JPB;

    __shared__ float sc_s[TLEN];
    __shared__ float red[NTHR];

    for (int t = tid; t < TLEN; t += NTHR) sc_s[t] = sc[t];
    __syncthreads();

    float lm = -INFINITY;
    for (int t = tid; t < TLEN; t += NTHR) lm = fmaxf(lm, sc_s[t]);
    red[tid] = lm; __syncthreads();
    for (int s2 = NTHR / 2; s2 > 0; s2 >>= 1) {
        if (tid < s2) red[tid] = fmaxf(red[tid], red[tid + s2]);
        __syncthreads();
    }
    const float m = red[0]; __syncthreads();
    float lz = 0.f;
    for (int t = tid; t < TLEN; t += NTHR) lz += __expf(sc_s[t] - m);
    red[tid] = lz; __syncthreads();
    for (int s2 = NTHR / 2; s2 > 0; s2 >>= 1) {
        if (tid < s2) red[tid] += red[tid + s2];
        __syncthreads();
    }
    const float Zi = 1.f / red[0]; __syncthreads();

    const int j = j0 + w;
    float a = 0.f;
    if (hsT) {
        const float* row = hsT + (size_t)j * TLEN;   // row[t] = hs[t+1][j]
#pragma unroll
        for (int it = 0; it < TLEN / 64; ++it) {
            const int t = lane + it * 64;
            a = fmaf(__expf(sc_s[t] - m) * Zi, row[t], a);
        }
    } else {
#pragma unroll
        for (int it = 0; it < TLEN / 64; ++it) {
            const int t = lane + it * 64;
            a = fmaf(__expf(sc_s[t] - m) * Zi, hs[(size_t)(t + 1) * HD + j], a);
        }
    }
#pragma unroll
    for (int off = 32; off > 0; off >>= 1) a += __shfl_down(a, off);
    if (lane == 0) dctx[j] = a;
}

// K4: ht_new = tanh(W_attn @ [d; ht] + b_attn)  (unchanged)
__global__ __launch_bounds__(256) void k_attn(
    const float* __restrict__ Wattn,
    const float* __restrict__ battn,
    float* __restrict__ wsf, int s)
{
    const float* dctx = wsf + OFF_DC;
    const float* hnxt = wsf + OFF_HD + (size_t)((s + 1) & 1) * HD;
    float* htn = wsf + OFF_HTN;

    const int b    = blockIdx.x;
    const int tid  = threadIdx.x;
    const int w    = tid >> 6;
    const int lane = tid & 63;
    const int j0   = b * JPB;

    __shared__ float bufAB[2 * HD];
    const float4* buf4 = (const float4*)bufAB;
    for (int i = tid; i < HD; i += NTHR) {
        bufAB[i]      = dctx[i];
        bufAB[HD + i] = hnxt[i];
    }
    __syncthreads();

    const int j = j0 + w;
    const float4* wr4 = (const float4*)(Wattn + (size_t)j * (2 * HD));
    float4 a4 = make_float4(0.f, 0.f, 0.f, 0.f);
#pragma unroll
    for (int q = 0; q < 8; ++q) {
        float4 wv = wr4[q * 64 + lane], bv = buf4[q * 64 + lane];
        a4.x = fmaf(wv.x, bv.x, a4.x); a4.y = fmaf(wv.y, bv.y, a4.y);
        a4.z = fmaf(wv.z, bv.z, a4.z); a4.w = fmaf(wv.w, bv.w, a4.w);
    }
    float a = (a4.x + a4.y) + (a4.z + a4.w);
#pragma unroll
    for (int off = 32; off > 0; off >>= 1) a += __shfl_down(a, off);
    if (lane == 0) htn[j] = tanhf(a + battn[j]);
}

// K5: logits + per-block argmax — 500 blocks x 64 rows (2 blocks/CU)
__global__ __launch_bounds__(256) void k_logits(
    const float* __restrict__ Wout,
    const float* __restrict__ bout,
    float* __restrict__ wsf,
    float* __restrict__ out, int s)
{
    const float* htn = wsf + OFF_HTN;
    float* bmv = wsf + OFF_BMV;
    int*   bmi = (int*)(wsf + OFF_BMI);
    const int* st = (const int*)(wsf + OFF_ST);

    const int b    = blockIdx.x;
    const int tid  = threadIdx.x;
    const int w    = tid >> 6;
    const int lane = tid & 63;

    __shared__ float bufH[HD];
    __shared__ float red[4];
    __shared__ int   redi[4];
    const float4* buf4 = (const float4*)bufH;

    const int donev = (st[s] >> 16) & 1;
    for (int i = tid; i < HD; i += NTHR) bufH[i] = htn[i];
    __syncthreads();

    const int rbeg = b * 64 + w * RPW_L;   // 16 rows per wave, all valid
    float bv = -INFINITY; int bi = 0x7fffffff;
    for (int r = rbeg; r < rbeg + RPW_L; r += 2) {
        const float4* w0 = (const float4*)(Wout + (size_t)r * HD);
        const float4* w1 = (const float4*)(Wout + (size_t)(r + 1) * HD);
        float4 a04 = make_float4(0.f, 0.f, 0.f, 0.f);
        float4 a14 = make_float4(0.f, 0.f, 0.f, 0.f);
#pragma unroll
        for (int q = 0; q < 4; ++q) {
            float4 hv = buf4[q * 64 + lane];
            float4 x0 = w0[q * 64 + lane];
            float4 x1 = w1[q * 64 + lane];
            a04.x = fmaf(x0.x, hv.x, a04.x); a04.y = fmaf(x0.y, hv.y, a04.y);
            a04.z = fmaf(x0.z, hv.z, a04.z); a04.w = fmaf(x0.w, hv.w, a04.w);
            a14.x = fmaf(x1.x, hv.x, a14.x); a14.y = fmaf(x1.y, hv.y, a14.y);
            a14.z = fmaf(x1.z, hv.z, a14.z); a14.w = fmaf(x1.w, hv.w, a14.w);
        }
        float a0 = (a04.x + a04.y) + (a04.z + a04.w);
        float a1 = (a14.x + a14.y) + (a14.z + a14.w);
#pragma unroll
        for (int off = 32; off > 0; off >>= 1) {
            a0 += __shfl_down(a0, off);
            a1 += __shfl_down(a1, off);
        }
        if (lane == 0) {
            a0 += bout[r];
            a1 += bout[r + 1];
            out[NSTEP + (size_t)s * VOUTN + r]     = donev ? 0.f : a0;
            out[NSTEP + (size_t)s * VOUTN + r + 1] = donev ? 0.f : a1;
            if (a0 > bv) { bv = a0; bi = r; }
            if (a1 > bv) { bv = a1; bi = r + 1; }
        }
    }
    if (lane == 0) { red[w] = bv; redi[w] = bi; }
    __syncthreads();
    if (tid == 0) {
        float v = red[0]; int ii = redi[0];
#pragma unroll
        for (int q = 1; q < 4; ++q)
            if (red[q] > v || (red[q] == v && redi[q] < ii)) { v = red[q]; ii = redi[q]; }
        bmv[b] = v; bmi[b] = ii;
    }
}

// K6 (final only): global argmax for step 49's token
__global__ __launch_bounds__(256) void k_amax_final(
    float* __restrict__ wsf, float* __restrict__ out)
{
    const float* bmv = wsf + OFF_BMV;
    const int*   bmi = (const int*)(wsf + OFF_BMI);
    const int*   st  = (const int*)(wsf + OFF_ST);

    const int tid = threadIdx.x;
    __shared__ float red[NTHR];
    __shared__ int   redi[NTHR];

    float v1 = bmv[tid]; int i1 = bmi[tid];
    if (tid + 256 < NBLK_L) {
        float v2 = bmv[tid + 256]; int i2 = bmi[tid + 256];
        if (v2 > v1 || (v2 == v1 && i2 < i1)) { v1 = v2; i1 = i2; }
    }
    red[tid] = v1; redi[tid] = i1;
    __syncthreads();
    for (int s2 = 128; s2 > 0; s2 >>= 1) {
        if (tid < s2) {
            if (red[tid + s2] > red[tid] ||
                (red[tid + s2] == red[tid] && redi[tid + s2] < redi[tid])) {
                red[tid] = red[tid + s2]; redi[tid] = redi[tid + s2];
            }
        }
        __syncthreads();
    }
    if (tid == 0) {
        const int nid   = redi[0];
        const int donev = (st[NSTEP - 1] >> 16) & 1;
        out[NSTEP - 1] = donev ? 0.f : (float)nid;
    }
}

extern "C" void kernel_launch(void* const* d_in, const int* in_sizes, int n_in,
                              void* d_out, int out_size, void* d_ws, size_t ws_size,
                              hipStream_t stream) {
    (void)in_sizes; (void)n_in; (void)out_size;
    const int*   src_ids = (const int*)  d_in[0];
    const float* emb_in  = (const float*)d_in[1];
    const float* We_ih   = (const float*)d_in[2];
    const float* We_hh   = (const float*)d_in[3];
    const float* be      = (const float*)d_in[4];
    const float* emb_tgt = (const float*)d_in[5];
    const float* Wd_ih   = (const float*)d_in[6];
    const float* Wd_hh   = (const float*)d_in[7];
    const float* bd      = (const float*)d_in[8];
    const float* W_attn  = (const float*)d_in[9];
    const float* b_attn  = (const float*)d_in[10];
    const float* W_out   = (const float*)d_in[11];
    const float* b_out   = (const float*)d_in[12];

    float* outp = (float*)d_out;
    float* wsf  = (float*)d_ws;

    const bool use_hsT = (ws_size >= WS_NEED_HST);
    const float* hsTp = use_hsT ? (wsf + OFF_HST) : nullptr;

    // deterministic init every call: h0 row zeros + sentinel rows 1..TLEN
    hipMemsetAsync(wsf + OFF_HS, 0, HD * sizeof(float), stream);
    fill_sentinel<<<TLEN, 256, 0, stream>>>(wsf + OFF_HS + HD);

    // Phase 1: Gx = X @ We_ih^T + be
    dim3 g1(TLEN / 128, G4H / 128);
    gx_gemm<<<g1, 256, 0, stream>>>(src_ids, emb_in, We_ih, be, wsf + OFF_GX);

    // Phase 2: encoder (cooperative; sentinel data-poll inside)
    {
        const float* a_Whh = We_hh;
        const float* a_Gx  = wsf + OFF_GX;
        float* a_ws  = wsf;
        void* args[] = { &a_Whh, &a_Gx, &a_ws };
        hipLaunchCooperativeKernel(reinterpret_cast<void*>(enc_kernel),
                                   dim3(ENBLK), dim3(ENTHR), args, 0, stream);
    }

    // Phase 2b: hs transpose for coalesced k_ctx (if workspace allows)
    if (use_hsT)
        k_transpose<<<dim3(TLEN / 32, HD / 32), 256, 0, stream>>>(
            wsf + OFF_HS, wsf + OFF_HST);

    // Phase 3: decoder — 5 kernels per step (argmax folded into next gates)
    for (int s = 0; s < NSTEP; ++s) {
        k_gates <<<NBLK,   NTHR, 0, stream>>>(emb_tgt, Wd_ih, Wd_hh, bd, wsf, outp, s);
        k_scores<<<NBLK,   NTHR, 0, stream>>>(wsf, s);
        k_ctx   <<<NBLK,   NTHR, 0, stream>>>(wsf, hsTp);
        k_attn  <<<NBLK,   NTHR, 0, stream>>>(W_attn, b_attn, wsf, s);
        k_logits<<<NBLK_L, NTHR, 0, stream>>>(W_out, b_out, wsf, outp, s);
    }
    k_amax_final<<<1, NTHR, 0, stream>>>(wsf, outp);
}